// Round 10
// baseline (455.690 us; speedup 1.0000x reference)
//
#include <hip/hip_runtime.h>
#include <math.h>

#define EMB 1024
#define NHEADS 16
#define HDIM 64
#define BATCH 2
#define SEQ 2048
#define MROWS (BATCH*SEQ)   /* 4096 */
#define LN_EPS 1e-5f
#define GK 1024
#define GN 1024

typedef __attribute__((ext_vector_type(8))) short bf16x8;
typedef __attribute__((ext_vector_type(4))) short s16x4;
typedef __attribute__((ext_vector_type(4))) float f32x4;
typedef __attribute__((ext_vector_type(4))) int int4v;

__device__ __forceinline__ short f2bf(float f) {     // RNE float->bf16
    union { float f; unsigned u; } v; v.f = f;
    unsigned r = v.u + 0x7FFFu + ((v.u >> 16) & 1u);
    return (short)(r >> 16);
}
__device__ __forceinline__ float bf2f(short s) {
    union { unsigned u; float f; } v; v.u = ((unsigned)(unsigned short)s) << 16;
    return v.f;
}
// truncating split: f = hi + lo + err, |err| <~ 2^-17 |f|
__device__ __forceinline__ void fsplit(float f, short& hi, short& lo) {
    const unsigned u = __float_as_uint(f);
    hi = (short)(u >> 16);
    const float r = f - __uint_as_float(u & 0xFFFF0000u);   // exact
    lo = (short)(__float_as_uint(r) >> 16);
}
__device__ __forceinline__ unsigned pk2(short a, short b) {
    return (unsigned)(unsigned short)a | ((unsigned)(unsigned short)b << 16);
}

__device__ __forceinline__ void gload16(const short* g, short* l) {
    __builtin_amdgcn_global_load_lds(
        (const __attribute__((address_space(1))) unsigned*)g,
        (__attribute__((address_space(3))) unsigned*)l, 16, 0, 0);
}

// ---------------------------------------------------------------------------
// fp32 -> split-bf16 planes. x input.
// ---------------------------------------------------------------------------
__global__ __launch_bounds__(256)
void cvt_split(const float* __restrict__ X, short* __restrict__ H,
               short* __restrict__ L)
{
    const size_t i = (size_t)blockIdx.x * 256 + threadIdx.x;
    const float4 v = *(const float4*)&X[i * 4];
    s16x4 h, l;
    short th, tl;
    fsplit(v.x, th, tl); h[0] = th; l[0] = tl;
    fsplit(v.y, th, tl); h[1] = th; l[1] = tl;
    fsplit(v.z, th, tl); h[2] = th; l[2] = tl;
    fsplit(v.w, th, tl); h[3] = th; l[3] = tl;
    *(s16x4*)&H[i * 4] = h;
    *(s16x4*)&L[i * 4] = l;
}

// all four weights -> 4 slots of (1M shorts) in H/L planes. grid (1024, 4)
__global__ __launch_bounds__(256)
void cvt_w4(const float* __restrict__ W0, const float* __restrict__ W1,
            const float* __restrict__ W2, const float* __restrict__ W3,
            short* __restrict__ H, short* __restrict__ L)
{
    const int z = blockIdx.y;
    const float* W = (z == 0) ? W0 : (z == 1) ? W1 : (z == 2) ? W2 : W3;
    const size_t i = (size_t)blockIdx.x * 256 + threadIdx.x;
    const size_t o = ((size_t)z << 20) + i * 4;
    const float4 v = *(const float4*)&W[i * 4];
    s16x4 h, l;
    short th, tl;
    fsplit(v.x, th, tl); h[0] = th; l[0] = tl;
    fsplit(v.y, th, tl); h[1] = th; l[1] = tl;
    fsplit(v.z, th, tl); h[2] = th; l[2] = tl;
    fsplit(v.w, th, tl); h[3] = th; l[3] = tl;
    *(s16x4*)&H[o] = h;
    *(s16x4*)&L[o] = l;
}

// ---------------------------------------------------------------------------
// Fused K/Q/V split-bf16 MFMA GEMM (unchanged from R8).
// ---------------------------------------------------------------------------
__global__ __launch_bounds__(256, 3)
void gemm_kqv(const short* __restrict__ Xh, const short* __restrict__ Xl,
              const short* __restrict__ W4h, const short* __restrict__ W4l,
              const float* __restrict__ kg, const float* __restrict__ kb,
              const float* __restrict__ qg, const float* __restrict__ qb,
              float scale,
              short* __restrict__ KhP, short* __restrict__ KlP,
              short* __restrict__ QhP, short* __restrict__ QlP,
              short* __restrict__ VTh, short* __restrict__ VTl)
{
    __shared__ short AhS[128][32], AlS[128][32], BhS[128][32], BlS[128][32];

    const int t   = threadIdx.x;
    const int ln  = t & 63, wv = t >> 6;
    const int l15 = ln & 15, l4 = ln >> 4;
    const int m0  = blockIdx.y * 128;
    const int n0  = blockIdx.x * 128;
    const int z   = blockIdx.z;
    const int wr  = (wv >> 1) * 64, wc = (wv & 1) * 64;

    const short* Bh = W4h + ((size_t)z << 20);
    const short* Bl = W4l + ((size_t)z << 20);

    const short* gplane = (wv == 0) ? Xh : (wv == 1) ? Xl : (wv == 2) ? Bh : Bl;
    const int    grow0  = (wv < 2) ? m0 : n0;
    short* lplane = (wv == 0) ? &AhS[0][0] : (wv == 1) ? &AlS[0][0]
                  : (wv == 2) ? &BhS[0][0] : &BlS[0][0];

    f32x4 acc[4][4];
    #pragma unroll
    for (int i = 0; i < 4; ++i)
        #pragma unroll
        for (int j = 0; j < 4; ++j) acc[i][j] = (f32x4){0.f, 0.f, 0.f, 0.f};

    for (int k0 = 0; k0 < GK; k0 += 32) {
        __syncthreads();
        #pragma unroll
        for (int s = 0; s < 8; ++s) {
            const int chunk = s * 64 + ln;
            const int r = chunk >> 2, c = chunk & 3;
            gload16(gplane + (size_t)(grow0 + r) * GK + k0 + c * 8,
                    lplane + s * 512);
        }
        __syncthreads();

        bf16x8 ah[4], al[4], bh[4], bl[4];
        #pragma unroll
        for (int f = 0; f < 4; ++f) {
            ah[f] = *(const bf16x8*)&AhS[wr + f * 16 + l15][l4 * 8];
            al[f] = *(const bf16x8*)&AlS[wr + f * 16 + l15][l4 * 8];
            bh[f] = *(const bf16x8*)&BhS[wc + f * 16 + l15][l4 * 8];
            bl[f] = *(const bf16x8*)&BlS[wc + f * 16 + l15][l4 * 8];
        }
        #pragma unroll
        for (int i = 0; i < 4; ++i)
            #pragma unroll
            for (int j = 0; j < 4; ++j) {
                acc[i][j] = __builtin_amdgcn_mfma_f32_16x16x32_bf16(ah[i], bh[j], acc[i][j], 0, 0, 0);
                acc[i][j] = __builtin_amdgcn_mfma_f32_16x16x32_bf16(ah[i], bl[j], acc[i][j], 0, 0, 0);
                acc[i][j] = __builtin_amdgcn_mfma_f32_16x16x32_bf16(al[i], bh[j], acc[i][j], 0, 0, 0);
            }
    }

    if (z < 2) {
        const float* gamma = (z == 0) ? kg : qg;
        const float* beta  = (z == 0) ? kb : qb;
        short* OutH = (z == 0) ? KhP : QhP;
        short* OutL = (z == 0) ? KlP : QlP;
        const int n_head = (n0 + wc) >> 6;
        float g4[4], b4[4];
        #pragma unroll
        for (int f = 0; f < 4; ++f) {
            g4[f] = gamma[f * 16 + l15];
            b4[f] = beta [f * 16 + l15];
        }
        #pragma unroll
        for (int i = 0; i < 4; ++i)
            #pragma unroll
            for (int j = 0; j < 4; ++j) {
                const float v0 = acc[i][0][j], v1 = acc[i][1][j];
                const float v2 = acc[i][2][j], v3 = acc[i][3][j];
                float s1 = v0 + v1 + v2 + v3;
                float s2 = v0*v0 + v1*v1 + v2*v2 + v3*v3;
                s1 += __shfl_xor(s1, 1); s2 += __shfl_xor(s2, 1);
                s1 += __shfl_xor(s1, 2); s2 += __shfl_xor(s2, 2);
                s1 += __shfl_xor(s1, 4); s2 += __shfl_xor(s2, 4);
                s1 += __shfl_xor(s1, 8); s2 += __shfl_xor(s2, 8);
                const float mu  = s1 * (1.f / 64.f);
                const float var = s2 * (1.f / 64.f) - mu * mu;
                const float rs  = rsqrtf(var + LN_EPS);
                const int m = m0 + wr + i * 16 + l4 * 4 + j;   // m = b*SEQ + t
                const size_t orow =
                    ((size_t)((m >> 11) * NHEADS + n_head) * SEQ + (m & (SEQ - 1))) * HDIM;
                #pragma unroll
                for (int f = 0; f < 4; ++f) {
                    const float y = ((acc[i][f][j] - mu) * rs * g4[f] + b4[f]) * scale;
                    short hi, lo; fsplit(y, hi, lo);
                    OutH[orow + f * 16 + l15] = hi;
                    OutL[orow + f * 16 + l15] = lo;
                }
            }
    } else {
        #pragma unroll
        for (int i = 0; i < 4; ++i)
            #pragma unroll
            for (int f = 0; f < 4; ++f) {
                s16x4 h4, l4v;
                #pragma unroll
                for (int j = 0; j < 4; ++j) {
                    short hi, lo; fsplit(acc[i][f][j], hi, lo);
                    h4[j] = hi; l4v[j] = lo;
                }
                const int n  = n0 + wc + f * 16 + l15;
                const int hh = n >> 6, dd = n & 63;
                const int mb = m0 + wr + i * 16 + l4 * 4;      // j=0 row
                const size_t oa =
                    (((size_t)((mb >> 11) * NHEADS + hh)) * HDIM + dd) * SEQ + (mb & (SEQ - 1));
                *(s16x4*)&VTh[oa] = h4;
                *(s16x4*)&VTl[oa] = l4v;
            }
    }
}

// ---------------------------------------------------------------------------
// Final GEMM (unchanged from R8).
// ---------------------------------------------------------------------------
__global__ __launch_bounds__(256, 2)
void gemm_out(const short* __restrict__ Ah, const short* __restrict__ Al,
              const short* __restrict__ Bh, const short* __restrict__ Bl,
              const float* __restrict__ bias, float* __restrict__ OutF)
{
    __shared__ short AhS[64][32], AlS[64][32], BhS[128][32], BlS[128][32];

    const int t   = threadIdx.x;
    const int ln  = t & 63, wv = t >> 6;
    const int l15 = ln & 15, l4 = ln >> 4;
    const int m0  = blockIdx.y * 64;
    const int n0  = blockIdx.x * 128;
    const int wr  = (wv >> 1) * 32, wc = (wv & 1) * 64;

    const short* gplane = (wv == 0) ? Ah : (wv == 1) ? Al : (wv == 2) ? Bh : Bl;
    const int    grow0  = (wv < 2) ? m0 : n0;
    const int    nseg   = (wv < 2) ? 4 : 8;
    short* lplane = (wv == 0) ? &AhS[0][0] : (wv == 1) ? &AlS[0][0]
                  : (wv == 2) ? &BhS[0][0] : &BlS[0][0];

    f32x4 acc[2][4];
    #pragma unroll
    for (int i = 0; i < 2; ++i)
        #pragma unroll
        for (int j = 0; j < 4; ++j) acc[i][j] = (f32x4){0.f, 0.f, 0.f, 0.f};

    for (int k0 = 0; k0 < GK; k0 += 32) {
        __syncthreads();
        for (int s = 0; s < nseg; ++s) {
            const int chunk = s * 64 + ln;
            const int r = chunk >> 2, c = chunk & 3;
            gload16(gplane + (size_t)(grow0 + r) * GK + k0 + c * 8,
                    lplane + s * 512);
        }
        __syncthreads();

        bf16x8 ah[2], al[2], bh[4], bl[4];
        #pragma unroll
        for (int f = 0; f < 2; ++f) {
            ah[f] = *(const bf16x8*)&AhS[wr + f * 16 + l15][l4 * 8];
            al[f] = *(const bf16x8*)&AlS[wr + f * 16 + l15][l4 * 8];
        }
        #pragma unroll
        for (int f = 0; f < 4; ++f) {
            bh[f] = *(const bf16x8*)&BhS[wc + f * 16 + l15][l4 * 8];
            bl[f] = *(const bf16x8*)&BlS[wc + f * 16 + l15][l4 * 8];
        }
        #pragma unroll
        for (int i = 0; i < 2; ++i)
            #pragma unroll
            for (int j = 0; j < 4; ++j) {
                acc[i][j] = __builtin_amdgcn_mfma_f32_16x16x32_bf16(ah[i], bh[j], acc[i][j], 0, 0, 0);
                acc[i][j] = __builtin_amdgcn_mfma_f32_16x16x32_bf16(ah[i], bl[j], acc[i][j], 0, 0, 0);
                acc[i][j] = __builtin_amdgcn_mfma_f32_16x16x32_bf16(al[i], bh[j], acc[i][j], 0, 0, 0);
            }
    }

    float b4[4];
    #pragma unroll
    for (int f = 0; f < 4; ++f) b4[f] = bias[n0 + wc + f * 16 + l15];
    #pragma unroll
    for (int i = 0; i < 2; ++i)
        #pragma unroll
        for (int j = 0; j < 4; ++j) {
            const int m = m0 + wr + i * 16 + l4 * 4 + j;
            const size_t row = (size_t)m * GN + n0 + wc;
            #pragma unroll
            for (int f = 0; f < 4; ++f)
                OutF[row + f * 16 + l15] = acc[i][f][j] + b4[f];
        }
}

// ---------------------------------------------------------------------------
// Causal flash attention, split-bf16 MFMA, SWAPPED QK^T (mfma(K,Q)):
// lane holds a full 16-value P chunk for q = lane&15 -> softmax with only
// 2 cross-lane shuffles; P packed to bf16 pairs in-register and staged via a
// 16KB wave-private swizzled buffer (8 b32 writes + 2 b128 reads per ks-half).
// K/V tiles [64][64] with 16B-granule XOR swizzle (g ^= row&7) on both the
// reg-staged write and frag reads -> conflict-free. LDS 48KB -> 3 blocks/CU.
// ---------------------------------------------------------------------------
__global__ __launch_bounds__(512, 6)
void attn_mfma(const short* __restrict__ Qh, const short* __restrict__ Ql,
               const short* __restrict__ Kh, const short* __restrict__ Kl,
               const short* __restrict__ Vh, const short* __restrict__ Vl,
               short* __restrict__ Oh, short* __restrict__ Ol)
{
    __shared__ short KhS[64][64], KlS[64][64];
    __shared__ short VhS[64][64], VlS[64][64];
    __shared__ unsigned Pu[8][16][32];     // per-wave P buffer (ks-half, hi|lo)

    const int t    = threadIdx.x;
    const int lane = t & 63, wv = t >> 6;            // 8 waves
    const int l15  = lane & 15, l4 = lane >> 4;
    const int qt   = (int)gridDim.x - 1 - (int)blockIdx.x;   // heavy first
    const int bh   = blockIdx.y;
    const int bb   = bh >> 4, hh = bh & 15;
    const int q0   = qt * 128;
    const int wq0  = wv * 16;
    const int swz  = (l15 & 7) << 2;                 // P-buffer u32 swizzle

    const size_t kpan = (size_t)bh * SEQ * HDIM;   // [t][d] panels (Q,K)
    const size_t vpan = (size_t)bh * HDIM * SEQ;   // [d][t] panels (V^T)

    // staging role: 1 x 16B granule per plane per thread
    const int sr   = t >> 3;              // row 0..63
    const int sc   = t & 7;               // granule
    const int scs  = (sc ^ (sr & 7)) * 8; // swizzled LDS short offset
    const int soff = sc * 8;              // global short offset

    // Q fragments (B operand: lane&15 = q row, l4*8 + 32ds = d)
    bf16x8 qfh[2], qfl[2];
    {
        const size_t qrow = kpan + (size_t)(q0 + wq0 + l15) * HDIM;
        #pragma unroll
        for (int ds = 0; ds < 2; ++ds) {
            qfh[ds] = *(const bf16x8*)&Qh[qrow + l4 * 8 + 32 * ds];
            qfl[ds] = *(const bf16x8*)&Ql[qrow + l4 * 8 + 32 * ds];
        }
    }

    f32x4 oacc[4];                 // [d-block]; row=q(l4*4+r), col=d(l15)
    float m_run = -1e30f, l_run = 0.f;   // state for q = wq0 + l15
    #pragma unroll
    for (int dn = 0; dn < 4; ++dn) oacc[dn] = (f32x4){0.f, 0.f, 0.f, 0.f};

    const int NT = 2 * qt + 2;

    int4v pKh, pKl, pVh, pVl;      // reg prefetch (T14)
    {
        pKh = *(const int4v*)&Kh[kpan + (size_t)sr * HDIM + soff];
        pKl = *(const int4v*)&Kl[kpan + (size_t)sr * HDIM + soff];
        pVh = *(const int4v*)&Vh[vpan + (size_t)sr * SEQ + soff];
        pVl = *(const int4v*)&Vl[vpan + (size_t)sr * SEQ + soff];
    }

    for (int kt = 0; kt < NT; ++kt) {
        const int k0 = kt * 64;

        __syncthreads();           // all waves done reading prev K/V

        *(int4v*)&KhS[sr][scs] = pKh;
        *(int4v*)&KlS[sr][scs] = pKl;
        *(int4v*)&VhS[sr][scs] = pVh;
        *(int4v*)&VlS[sr][scs] = pVl;

        if (kt + 1 < NT) {         // issue next tile's loads under compute
            const int kn = k0 + 64;
            pKh = *(const int4v*)&Kh[kpan + (size_t)(kn + sr) * HDIM + soff];
            pKl = *(const int4v*)&Kl[kpan + (size_t)(kn + sr) * HDIM + soff];
            pVh = *(const int4v*)&Vh[vpan + (size_t)sr * SEQ + kn + soff];
            pVl = *(const int4v*)&Vl[vpan + (size_t)sr * SEQ + kn + soff];
        }
        __syncthreads();           // current tile's LDS ready

        if (k0 > q0 + wq0 + 15) continue;   // tile entirely future for wave

        // ---- QK^T swapped: s[kn] rows=k, cols=q ----
        f32x4 s[4];
        #pragma unroll
        for (int kn = 0; kn < 4; ++kn) s[kn] = (f32x4){0.f, 0.f, 0.f, 0.f};

        #pragma unroll
        for (int ds = 0; ds < 2; ++ds) {
            #pragma unroll
            for (int kn = 0; kn < 4; ++kn) {
                const int row = kn * 16 + l15;
                const int g   = ((l4 + 4 * ds) ^ (l15 & 7)) * 8;
                const bf16x8 kh = *(const bf16x8*)&KhS[row][g];
                const bf16x8 kl = *(const bf16x8*)&KlS[row][g];
                s[kn] = __builtin_amdgcn_mfma_f32_16x16x32_bf16(kh, qfh[ds], s[kn], 0, 0, 0);
                s[kn] = __builtin_amdgcn_mfma_f32_16x16x32_bf16(kh, qfl[ds], s[kn], 0, 0, 0);
                s[kn] = __builtin_amdgcn_mfma_f32_16x16x32_bf16(kl, qfh[ds], s[kn], 0, 0, 0);
            }
        }

        if (k0 + 63 > q0 + wq0) {  // causal mask (diag kept)
            const int qg_ = q0 + wq0 + l15;
            #pragma unroll
            for (int kn = 0; kn < 4; ++kn)
                #pragma unroll
                for (int r = 0; r < 4; ++r) {
                    const int kg_ = k0 + kn * 16 + l4 * 4 + r;
                    if (kg_ > qg_) s[kn][r] = -1e30f;
                }
        }

        // ---- online softmax (per lane: q = wq0 + l15) ----
        {
            float mx = -1e30f;
            #pragma unroll
            for (int kn = 0; kn < 4; ++kn)
                #pragma unroll
                for (int r = 0; r < 4; ++r) mx = fmaxf(mx, s[kn][r]);
            mx = fmaxf(mx, __shfl_xor(mx, 16));
            mx = fmaxf(mx, __shfl_xor(mx, 32));
            const float mnew = fmaxf(m_run, mx);
            const float scf  = __expf(m_run - mnew);
            m_run = mnew;
            float ls = 0.f;
            #pragma unroll
            for (int kn = 0; kn < 4; ++kn)
                #pragma unroll
                for (int r = 0; r < 4; ++r) {
                    const float p = __expf(s[kn][r] - mnew);
                    s[kn][r] = p;
                    ls += p;
                }
            ls += __shfl_xor(ls, 16);
            ls += __shfl_xor(ls, 32);
            l_run = l_run * scf + ls;
            // rescale oacc: row r is q_local = l4*4 + r -> fetch that q's scf
            float scr[4];
            #pragma unroll
            for (int r = 0; r < 4; ++r) scr[r] = __shfl(scf, l4 * 4 + r);
            #pragma unroll
            for (int dn = 0; dn < 4; ++dn)
                #pragma unroll
                for (int r = 0; r < 4; ++r) oacc[dn][r] *= scr[r];
        }

        // ---- PV per 32-k half: pack P, stage via wave-private LDS, MFMA ----
        #pragma unroll
        for (int ks = 0; ks < 2; ++ks) {
            #pragma unroll
            for (int nfo = 0; nfo < 2; ++nfo) {
                const int kn = 2 * ks + nfo;
                #pragma unroll
                for (int half = 0; half < 2; ++half) {
                    const float p0 = s[kn][2 * half];
                    const float p1 = s[kn][2 * half + 1];
                    const short h0 = f2bf(p0), h1 = f2bf(p1);
                    const short e0 = f2bf(p0 - bf2f(h0));
                    const short e1 = f2bf(p1 - bf2f(h1));
                    const int sl = nfo * 8 + 2 * l4 + half;       // 0..15
                    Pu[wv][l15][sl ^ swz]        = pk2(h0, h1);
                    Pu[wv][l15][(16 + sl) ^ swz] = pk2(e0, e1);
                }
            }
            asm volatile("s_waitcnt lgkmcnt(0)" ::: "memory");    // wave-local

            const bf16x8 pah = *(const bf16x8*)&Pu[wv][l15][(4 * l4) ^ swz];
            const bf16x8 pal = *(const bf16x8*)&Pu[wv][l15][(16 + 4 * l4) ^ swz];
            #pragma unroll
            for (int dn = 0; dn < 4; ++dn) {
                const int row = dn * 16 + l15;
                const int g   = ((l4 + 4 * ks) ^ (l15 & 7)) * 8;
                const bf16x8 vh = *(const bf16x8*)&VhS[row][g];
                const bf16x8 vl = *(const bf16x8*)&VlS[row][g];
                oacc[dn] = __builtin_amdgcn_mfma_f32_16x16x32_bf16(pah, vh, oacc[dn], 0, 0, 0);
                oacc[dn] = __builtin_amdgcn_mfma_f32_16x16x32_bf16(pah, vl, oacc[dn], 0, 0, 0);
                oacc[dn] = __builtin_amdgcn_mfma_f32_16x16x32_bf16(pal, vh, oacc[dn], 0, 0, 0);
            }
        }
    }

    // epilogue: normalize (l for q=row via shuffle), fsplit, write split planes
    float invr[4];
    #pragma unroll
    for (int r = 0; r < 4; ++r) invr[r] = 1.f / __shfl(l_run, l4 * 4 + r);
    #pragma unroll
    for (int r = 0; r < 4; ++r) {
        const int q = q0 + wq0 + l4 * 4 + r;
        const size_t row = ((size_t)(bb * SEQ + q)) * EMB + hh * HDIM;
        #pragma unroll
        for (int dn = 0; dn < 4; ++dn) {
            short hi, lo; fsplit(oacc[dn][r] * invr[r], hi, lo);
            Oh[row + dn * 16 + l15] = hi;
            Ol[row + dn * 16 + l15] = lo;
        }
    }
}

// ---------------------------------------------------------------------------
extern "C" void kernel_launch(void* const* d_in, const int* in_sizes, int n_in,
                              void* d_out, int out_size, void* d_ws, size_t ws_size,
                              hipStream_t stream)
{
    const float* x  = (const float*)d_in[0];
    const float* Wk = (const float*)d_in[1];
    const float* Wq = (const float*)d_in[2];
    const float* Wv = (const float*)d_in[3];
    const float* Wu = (const float*)d_in[4];
    const float* bu = (const float*)d_in[5];
    const float* kg = (const float*)d_in[6];
    const float* kb = (const float*)d_in[7];
    const float* qg = (const float*)d_in[8];
    const float* qb = (const float*)d_in[9];
    float* out = (float*)d_out;

    // ws map (64 MB):
    //  [ 0,16M) Xh|Xl   -> reused as Oh|Ol after KQV GEMMs
    //  [16,32M) Kh|Kl
    //  [32,48M) Qh|Ql
    //  [48,64M) W4h (4x2MB) | W4l (4x2MB)
    // d_out doubles as: V^T split panels (KQV z=2 out) -> final fp32 out
    char* w = (char*)d_ws;
    short* XhP = (short*)(w);
    short* XlP = (short*)(w + (8u  << 20));
    short* KhP = (short*)(w + (16u << 20));
    short* KlP = (short*)(w + (24u << 20));
    short* QhP = (short*)(w + (32u << 20));
    short* QlP = (short*)(w + (40u << 20));
    short* W4h = (short*)(w + (48u << 20));
    short* W4l = (short*)(w + (56u << 20));
    short* VTh = (short*)d_out;
    short* VTl = (short*)d_out + (4u << 20);   // +8 MB

    const float inv4 = 0.17677669529663687f;   // 1024^(-1/4)

    cvt_split<<<4096, 256, 0, stream>>>(x, XhP, XlP);
    cvt_w4<<<dim3(1024, 4), 256, 0, stream>>>(Wk, Wq, Wv, Wu, W4h, W4l);

    gemm_kqv<<<dim3(GN / 128, MROWS / 128, 3), 256, 0, stream>>>(
        XhP, XlP, W4h, W4l, kg, kb, qg, qb, inv4,
        KhP, KlP, QhP, QlP, VTh, VTl);

    attn_mfma<<<dim3(SEQ / 128, BATCH * NHEADS), 512, 0, stream>>>(
        QhP, QlP, KhP, KlP, VTh, VTl, XhP, XlP);

    gemm_out<<<dim3(GN / 128, MROWS / 64), 256, 0, stream>>>(
        XhP, XlP, W4h + (3u << 20), W4l + (3u << 20), bu, out);
}

// Round 11
// 256.653 us; speedup vs baseline: 1.7755x; 1.7755x over previous
//
#include <hip/hip_runtime.h>
#include <math.h>

#define EMB 1024
#define NHEADS 16
#define HDIM 64
#define BATCH 2
#define SEQ 2048
#define MROWS (BATCH*SEQ)   /* 4096 */
#define LN_EPS 1e-5f
#define GK 1024
#define GN 1024

typedef __attribute__((ext_vector_type(8))) short bf16x8;
typedef __attribute__((ext_vector_type(4))) short s16x4;
typedef __attribute__((ext_vector_type(4))) float f32x4;
typedef __attribute__((ext_vector_type(4))) int int4v;

__device__ __forceinline__ short f2bf(float f) {     // RNE float->bf16
    union { float f; unsigned u; } v; v.f = f;
    unsigned r = v.u + 0x7FFFu + ((v.u >> 16) & 1u);
    return (short)(r >> 16);
}
__device__ __forceinline__ float bf2f(short s) {
    union { unsigned u; float f; } v; v.u = ((unsigned)(unsigned short)s) << 16;
    return v.f;
}
// truncating split: f = hi + lo + err, |err| <~ 2^-17 |f|
__device__ __forceinline__ void fsplit(float f, short& hi, short& lo) {
    const unsigned u = __float_as_uint(f);
    hi = (short)(u >> 16);
    const float r = f - __uint_as_float(u & 0xFFFF0000u);   // exact
    lo = (short)(__float_as_uint(r) >> 16);
}
__device__ __forceinline__ unsigned pk2(short a, short b) {
    return (unsigned)(unsigned short)a | ((unsigned)(unsigned short)b << 16);
}

__device__ __forceinline__ void gload16(const short* g, short* l) {
    __builtin_amdgcn_global_load_lds(
        (const __attribute__((address_space(1))) unsigned*)g,
        (__attribute__((address_space(3))) unsigned*)l, 16, 0, 0);
}

// ---------------------------------------------------------------------------
// fp32 -> split-bf16 planes. x input.
// ---------------------------------------------------------------------------
__global__ __launch_bounds__(256)
void cvt_split(const float* __restrict__ X, short* __restrict__ H,
               short* __restrict__ L)
{
    const size_t i = (size_t)blockIdx.x * 256 + threadIdx.x;
    const float4 v = *(const float4*)&X[i * 4];
    s16x4 h, l;
    short th, tl;
    fsplit(v.x, th, tl); h[0] = th; l[0] = tl;
    fsplit(v.y, th, tl); h[1] = th; l[1] = tl;
    fsplit(v.z, th, tl); h[2] = th; l[2] = tl;
    fsplit(v.w, th, tl); h[3] = th; l[3] = tl;
    *(s16x4*)&H[i * 4] = h;
    *(s16x4*)&L[i * 4] = l;
}

// all four weights -> 4 slots of (1M shorts) in H/L planes. grid (1024, 4)
__global__ __launch_bounds__(256)
void cvt_w4(const float* __restrict__ W0, const float* __restrict__ W1,
            const float* __restrict__ W2, const float* __restrict__ W3,
            short* __restrict__ H, short* __restrict__ L)
{
    const int z = blockIdx.y;
    const float* W = (z == 0) ? W0 : (z == 1) ? W1 : (z == 2) ? W2 : W3;
    const size_t i = (size_t)blockIdx.x * 256 + threadIdx.x;
    const size_t o = ((size_t)z << 20) + i * 4;
    const float4 v = *(const float4*)&W[i * 4];
    s16x4 h, l;
    short th, tl;
    fsplit(v.x, th, tl); h[0] = th; l[0] = tl;
    fsplit(v.y, th, tl); h[1] = th; l[1] = tl;
    fsplit(v.z, th, tl); h[2] = th; l[2] = tl;
    fsplit(v.w, th, tl); h[3] = th; l[3] = tl;
    *(s16x4*)&H[o] = h;
    *(s16x4*)&L[o] = l;
}

// ---------------------------------------------------------------------------
// Fused K/Q/V split-bf16 MFMA GEMM (unchanged from R8).
// ---------------------------------------------------------------------------
__global__ __launch_bounds__(256, 3)
void gemm_kqv(const short* __restrict__ Xh, const short* __restrict__ Xl,
              const short* __restrict__ W4h, const short* __restrict__ W4l,
              const float* __restrict__ kg, const float* __restrict__ kb,
              const float* __restrict__ qg, const float* __restrict__ qb,
              float scale,
              short* __restrict__ KhP, short* __restrict__ KlP,
              short* __restrict__ QhP, short* __restrict__ QlP,
              short* __restrict__ VTh, short* __restrict__ VTl)
{
    __shared__ short AhS[128][32], AlS[128][32], BhS[128][32], BlS[128][32];

    const int t   = threadIdx.x;
    const int ln  = t & 63, wv = t >> 6;
    const int l15 = ln & 15, l4 = ln >> 4;
    const int m0  = blockIdx.y * 128;
    const int n0  = blockIdx.x * 128;
    const int z   = blockIdx.z;
    const int wr  = (wv >> 1) * 64, wc = (wv & 1) * 64;

    const short* Bh = W4h + ((size_t)z << 20);
    const short* Bl = W4l + ((size_t)z << 20);

    const short* gplane = (wv == 0) ? Xh : (wv == 1) ? Xl : (wv == 2) ? Bh : Bl;
    const int    grow0  = (wv < 2) ? m0 : n0;
    short* lplane = (wv == 0) ? &AhS[0][0] : (wv == 1) ? &AlS[0][0]
                  : (wv == 2) ? &BhS[0][0] : &BlS[0][0];

    f32x4 acc[4][4];
    #pragma unroll
    for (int i = 0; i < 4; ++i)
        #pragma unroll
        for (int j = 0; j < 4; ++j) acc[i][j] = (f32x4){0.f, 0.f, 0.f, 0.f};

    for (int k0 = 0; k0 < GK; k0 += 32) {
        __syncthreads();
        #pragma unroll
        for (int s = 0; s < 8; ++s) {
            const int chunk = s * 64 + ln;
            const int r = chunk >> 2, c = chunk & 3;
            gload16(gplane + (size_t)(grow0 + r) * GK + k0 + c * 8,
                    lplane + s * 512);
        }
        __syncthreads();

        bf16x8 ah[4], al[4], bh[4], bl[4];
        #pragma unroll
        for (int f = 0; f < 4; ++f) {
            ah[f] = *(const bf16x8*)&AhS[wr + f * 16 + l15][l4 * 8];
            al[f] = *(const bf16x8*)&AlS[wr + f * 16 + l15][l4 * 8];
            bh[f] = *(const bf16x8*)&BhS[wc + f * 16 + l15][l4 * 8];
            bl[f] = *(const bf16x8*)&BlS[wc + f * 16 + l15][l4 * 8];
        }
        #pragma unroll
        for (int i = 0; i < 4; ++i)
            #pragma unroll
            for (int j = 0; j < 4; ++j) {
                acc[i][j] = __builtin_amdgcn_mfma_f32_16x16x32_bf16(ah[i], bh[j], acc[i][j], 0, 0, 0);
                acc[i][j] = __builtin_amdgcn_mfma_f32_16x16x32_bf16(ah[i], bl[j], acc[i][j], 0, 0, 0);
                acc[i][j] = __builtin_amdgcn_mfma_f32_16x16x32_bf16(al[i], bh[j], acc[i][j], 0, 0, 0);
            }
    }

    if (z < 2) {
        const float* gamma = (z == 0) ? kg : qg;
        const float* beta  = (z == 0) ? kb : qb;
        short* OutH = (z == 0) ? KhP : QhP;
        short* OutL = (z == 0) ? KlP : QlP;
        const int n_head = (n0 + wc) >> 6;
        float g4[4], b4[4];
        #pragma unroll
        for (int f = 0; f < 4; ++f) {
            g4[f] = gamma[f * 16 + l15];
            b4[f] = beta [f * 16 + l15];
        }
        #pragma unroll
        for (int i = 0; i < 4; ++i)
            #pragma unroll
            for (int j = 0; j < 4; ++j) {
                const float v0 = acc[i][0][j], v1 = acc[i][1][j];
                const float v2 = acc[i][2][j], v3 = acc[i][3][j];
                float s1 = v0 + v1 + v2 + v3;
                float s2 = v0*v0 + v1*v1 + v2*v2 + v3*v3;
                s1 += __shfl_xor(s1, 1); s2 += __shfl_xor(s2, 1);
                s1 += __shfl_xor(s1, 2); s2 += __shfl_xor(s2, 2);
                s1 += __shfl_xor(s1, 4); s2 += __shfl_xor(s2, 4);
                s1 += __shfl_xor(s1, 8); s2 += __shfl_xor(s2, 8);
                const float mu  = s1 * (1.f / 64.f);
                const float var = s2 * (1.f / 64.f) - mu * mu;
                const float rs  = rsqrtf(var + LN_EPS);
                const int m = m0 + wr + i * 16 + l4 * 4 + j;   // m = b*SEQ + t
                const size_t orow =
                    ((size_t)((m >> 11) * NHEADS + n_head) * SEQ + (m & (SEQ - 1))) * HDIM;
                #pragma unroll
                for (int f = 0; f < 4; ++f) {
                    const float y = ((acc[i][f][j] - mu) * rs * g4[f] + b4[f]) * scale;
                    short hi, lo; fsplit(y, hi, lo);
                    OutH[orow + f * 16 + l15] = hi;
                    OutL[orow + f * 16 + l15] = lo;
                }
            }
    } else {
        #pragma unroll
        for (int i = 0; i < 4; ++i)
            #pragma unroll
            for (int f = 0; f < 4; ++f) {
                s16x4 h4, l4v;
                #pragma unroll
                for (int j = 0; j < 4; ++j) {
                    short hi, lo; fsplit(acc[i][f][j], hi, lo);
                    h4[j] = hi; l4v[j] = lo;
                }
                const int n  = n0 + wc + f * 16 + l15;
                const int hh = n >> 6, dd = n & 63;
                const int mb = m0 + wr + i * 16 + l4 * 4;      // j=0 row
                const size_t oa =
                    (((size_t)((mb >> 11) * NHEADS + hh)) * HDIM + dd) * SEQ + (mb & (SEQ - 1));
                *(s16x4*)&VTh[oa] = h4;
                *(s16x4*)&VTl[oa] = l4v;
            }
    }
}

// ---------------------------------------------------------------------------
// Final GEMM (unchanged from R8).
// ---------------------------------------------------------------------------
__global__ __launch_bounds__(256, 2)
void gemm_out(const short* __restrict__ Ah, const short* __restrict__ Al,
              const short* __restrict__ Bh, const short* __restrict__ Bl,
              const float* __restrict__ bias, float* __restrict__ OutF)
{
    __shared__ short AhS[64][32], AlS[64][32], BhS[128][32], BlS[128][32];

    const int t   = threadIdx.x;
    const int ln  = t & 63, wv = t >> 6;
    const int l15 = ln & 15, l4 = ln >> 4;
    const int m0  = blockIdx.y * 64;
    const int n0  = blockIdx.x * 128;
    const int wr  = (wv >> 1) * 32, wc = (wv & 1) * 64;

    const short* gplane = (wv == 0) ? Ah : (wv == 1) ? Al : (wv == 2) ? Bh : Bl;
    const int    grow0  = (wv < 2) ? m0 : n0;
    const int    nseg   = (wv < 2) ? 4 : 8;
    short* lplane = (wv == 0) ? &AhS[0][0] : (wv == 1) ? &AlS[0][0]
                  : (wv == 2) ? &BhS[0][0] : &BlS[0][0];

    f32x4 acc[2][4];
    #pragma unroll
    for (int i = 0; i < 2; ++i)
        #pragma unroll
        for (int j = 0; j < 4; ++j) acc[i][j] = (f32x4){0.f, 0.f, 0.f, 0.f};

    for (int k0 = 0; k0 < GK; k0 += 32) {
        __syncthreads();
        for (int s = 0; s < nseg; ++s) {
            const int chunk = s * 64 + ln;
            const int r = chunk >> 2, c = chunk & 3;
            gload16(gplane + (size_t)(grow0 + r) * GK + k0 + c * 8,
                    lplane + s * 512);
        }
        __syncthreads();

        bf16x8 ah[2], al[2], bh[4], bl[4];
        #pragma unroll
        for (int f = 0; f < 2; ++f) {
            ah[f] = *(const bf16x8*)&AhS[wr + f * 16 + l15][l4 * 8];
            al[f] = *(const bf16x8*)&AlS[wr + f * 16 + l15][l4 * 8];
        }
        #pragma unroll
        for (int f = 0; f < 4; ++f) {
            bh[f] = *(const bf16x8*)&BhS[wc + f * 16 + l15][l4 * 8];
            bl[f] = *(const bf16x8*)&BlS[wc + f * 16 + l15][l4 * 8];
        }
        #pragma unroll
        for (int i = 0; i < 2; ++i)
            #pragma unroll
            for (int j = 0; j < 4; ++j) {
                acc[i][j] = __builtin_amdgcn_mfma_f32_16x16x32_bf16(ah[i], bh[j], acc[i][j], 0, 0, 0);
                acc[i][j] = __builtin_amdgcn_mfma_f32_16x16x32_bf16(ah[i], bl[j], acc[i][j], 0, 0, 0);
                acc[i][j] = __builtin_amdgcn_mfma_f32_16x16x32_bf16(al[i], bh[j], acc[i][j], 0, 0, 0);
            }
    }

    float b4[4];
    #pragma unroll
    for (int f = 0; f < 4; ++f) b4[f] = bias[n0 + wc + f * 16 + l15];
    #pragma unroll
    for (int i = 0; i < 2; ++i)
        #pragma unroll
        for (int j = 0; j < 4; ++j) {
            const int m = m0 + wr + i * 16 + l4 * 4 + j;
            const size_t row = (size_t)m * GN + n0 + wc;
            #pragma unroll
            for (int f = 0; f < 4; ++f)
                OutF[row + f * 16 + l15] = acc[i][f][j] + b4[f];
        }
}

// ---------------------------------------------------------------------------
// Causal flash attention, split-bf16 MFMA, SWAPPED QK^T (mfma(K,Q)):
// lane holds a full 16-value P chunk for q = lane&15 -> softmax with only
// 2 cross-lane shuffles; P packed to bf16 pairs in-register and staged via a
// 16KB wave-private swizzled buffer. K/V tiles [64][64] with 16B-granule XOR
// swizzle on both write and read -> conflict-free.
// __launch_bounds__(512,4): VGPR cap 128 — (512,6) capped at ~85 and SPILLED
// (R10: VGPR=40, FETCH 418MB scratch traffic, 2x slower). LDS 48KB.
// ---------------------------------------------------------------------------
__global__ __launch_bounds__(512, 4)
void attn_mfma(const short* __restrict__ Qh, const short* __restrict__ Ql,
               const short* __restrict__ Kh, const short* __restrict__ Kl,
               const short* __restrict__ Vh, const short* __restrict__ Vl,
               short* __restrict__ Oh, short* __restrict__ Ol)
{
    __shared__ short KhS[64][64], KlS[64][64];
    __shared__ short VhS[64][64], VlS[64][64];
    __shared__ unsigned Pu[8][16][32];     // per-wave P buffer (ks-half, hi|lo)

    const int t    = threadIdx.x;
    const int lane = t & 63, wv = t >> 6;            // 8 waves
    const int l15  = lane & 15, l4 = lane >> 4;
    const int qt   = (int)gridDim.x - 1 - (int)blockIdx.x;   // heavy first
    const int bh   = blockIdx.y;
    const int bb   = bh >> 4, hh = bh & 15;
    const int q0   = qt * 128;
    const int wq0  = wv * 16;
    const int swz  = (l15 & 7) << 2;                 // P-buffer u32 swizzle

    const size_t kpan = (size_t)bh * SEQ * HDIM;   // [t][d] panels (Q,K)
    const size_t vpan = (size_t)bh * HDIM * SEQ;   // [d][t] panels (V^T)

    // staging role: 1 x 16B granule per plane per thread
    const int sr   = t >> 3;              // row 0..63
    const int sc   = t & 7;               // granule
    const int scs  = (sc ^ (sr & 7)) * 8; // swizzled LDS short offset
    const int soff = sc * 8;              // global short offset

    // Q fragments (B operand: lane&15 = q row, l4*8 + 32ds = d)
    bf16x8 qfh[2], qfl[2];
    {
        const size_t qrow = kpan + (size_t)(q0 + wq0 + l15) * HDIM;
        #pragma unroll
        for (int ds = 0; ds < 2; ++ds) {
            qfh[ds] = *(const bf16x8*)&Qh[qrow + l4 * 8 + 32 * ds];
            qfl[ds] = *(const bf16x8*)&Ql[qrow + l4 * 8 + 32 * ds];
        }
    }

    f32x4 oacc[4];                 // [d-block]; row=q(l4*4+r), col=d(l15)
    float m_run = -1e30f, l_run = 0.f;   // state for q = wq0 + l15
    #pragma unroll
    for (int dn = 0; dn < 4; ++dn) oacc[dn] = (f32x4){0.f, 0.f, 0.f, 0.f};

    const int NT = 2 * qt + 2;

    int4v pKh, pKl, pVh, pVl;      // reg prefetch (T14)
    {
        pKh = *(const int4v*)&Kh[kpan + (size_t)sr * HDIM + soff];
        pKl = *(const int4v*)&Kl[kpan + (size_t)sr * HDIM + soff];
        pVh = *(const int4v*)&Vh[vpan + (size_t)sr * SEQ + soff];
        pVl = *(const int4v*)&Vl[vpan + (size_t)sr * SEQ + soff];
    }

    for (int kt = 0; kt < NT; ++kt) {
        const int k0 = kt * 64;

        __syncthreads();           // all waves done reading prev K/V

        *(int4v*)&KhS[sr][scs] = pKh;
        *(int4v*)&KlS[sr][scs] = pKl;
        *(int4v*)&VhS[sr][scs] = pVh;
        *(int4v*)&VlS[sr][scs] = pVl;

        if (kt + 1 < NT) {         // issue next tile's loads under compute
            const int kn = k0 + 64;
            pKh = *(const int4v*)&Kh[kpan + (size_t)(kn + sr) * HDIM + soff];
            pKl = *(const int4v*)&Kl[kpan + (size_t)(kn + sr) * HDIM + soff];
            pVh = *(const int4v*)&Vh[vpan + (size_t)sr * SEQ + kn + soff];
            pVl = *(const int4v*)&Vl[vpan + (size_t)sr * SEQ + kn + soff];
        }
        __syncthreads();           // current tile's LDS ready

        if (k0 > q0 + wq0 + 15) continue;   // tile entirely future for wave

        // ---- QK^T swapped: s[kn] rows=k, cols=q ----
        f32x4 s[4];
        #pragma unroll
        for (int kn = 0; kn < 4; ++kn) s[kn] = (f32x4){0.f, 0.f, 0.f, 0.f};

        #pragma unroll
        for (int ds = 0; ds < 2; ++ds) {
            #pragma unroll
            for (int kn = 0; kn < 4; ++kn) {
                const int row = kn * 16 + l15;
                const int g   = ((l4 + 4 * ds) ^ (l15 & 7)) * 8;
                const bf16x8 kh = *(const bf16x8*)&KhS[row][g];
                const bf16x8 kl = *(const bf16x8*)&KlS[row][g];
                s[kn] = __builtin_amdgcn_mfma_f32_16x16x32_bf16(kh, qfh[ds], s[kn], 0, 0, 0);
                s[kn] = __builtin_amdgcn_mfma_f32_16x16x32_bf16(kh, qfl[ds], s[kn], 0, 0, 0);
                s[kn] = __builtin_amdgcn_mfma_f32_16x16x32_bf16(kl, qfh[ds], s[kn], 0, 0, 0);
            }
        }

        if (k0 + 63 > q0 + wq0) {  // causal mask (diag kept)
            const int qg_ = q0 + wq0 + l15;
            #pragma unroll
            for (int kn = 0; kn < 4; ++kn)
                #pragma unroll
                for (int r = 0; r < 4; ++r) {
                    const int kg_ = k0 + kn * 16 + l4 * 4 + r;
                    if (kg_ > qg_) s[kn][r] = -1e30f;
                }
        }

        // ---- online softmax (per lane: q = wq0 + l15) ----
        {
            float mx = -1e30f;
            #pragma unroll
            for (int kn = 0; kn < 4; ++kn)
                #pragma unroll
                for (int r = 0; r < 4; ++r) mx = fmaxf(mx, s[kn][r]);
            mx = fmaxf(mx, __shfl_xor(mx, 16));
            mx = fmaxf(mx, __shfl_xor(mx, 32));
            const float mnew = fmaxf(m_run, mx);
            const float scf  = __expf(m_run - mnew);
            m_run = mnew;
            float ls = 0.f;
            #pragma unroll
            for (int kn = 0; kn < 4; ++kn)
                #pragma unroll
                for (int r = 0; r < 4; ++r) {
                    const float p = __expf(s[kn][r] - mnew);
                    s[kn][r] = p;
                    ls += p;
                }
            ls += __shfl_xor(ls, 16);
            ls += __shfl_xor(ls, 32);
            l_run = l_run * scf + ls;
            // rescale oacc: row r is q_local = l4*4 + r -> fetch that q's scf
            float scr[4];
            #pragma unroll
            for (int r = 0; r < 4; ++r) scr[r] = __shfl(scf, l4 * 4 + r);
            #pragma unroll
            for (int dn = 0; dn < 4; ++dn)
                #pragma unroll
                for (int r = 0; r < 4; ++r) oacc[dn][r] *= scr[r];
        }

        // ---- PV per 32-k half: pack P, stage via wave-private LDS, MFMA ----
        #pragma unroll
        for (int ks = 0; ks < 2; ++ks) {
            #pragma unroll
            for (int nfo = 0; nfo < 2; ++nfo) {
                const int kn = 2 * ks + nfo;
                #pragma unroll
                for (int half = 0; half < 2; ++half) {
                    const float p0 = s[kn][2 * half];
                    const float p1 = s[kn][2 * half + 1];
                    const short h0 = f2bf(p0), h1 = f2bf(p1);
                    const short e0 = f2bf(p0 - bf2f(h0));
                    const short e1 = f2bf(p1 - bf2f(h1));
                    const int sl = nfo * 8 + 2 * l4 + half;       // 0..15
                    Pu[wv][l15][sl ^ swz]        = pk2(h0, h1);
                    Pu[wv][l15][(16 + sl) ^ swz] = pk2(e0, e1);
                }
            }
            asm volatile("s_waitcnt lgkmcnt(0)" ::: "memory");    // wave-local

            const bf16x8 pah = *(const bf16x8*)&Pu[wv][l15][(4 * l4) ^ swz];
            const bf16x8 pal = *(const bf16x8*)&Pu[wv][l15][(16 + 4 * l4) ^ swz];
            #pragma unroll
            for (int dn = 0; dn < 4; ++dn) {
                const int row = dn * 16 + l15;
                const int g   = ((l4 + 4 * ks) ^ (l15 & 7)) * 8;
                const bf16x8 vh = *(const bf16x8*)&VhS[row][g];
                const bf16x8 vl = *(const bf16x8*)&VlS[row][g];
                oacc[dn] = __builtin_amdgcn_mfma_f32_16x16x32_bf16(pah, vh, oacc[dn], 0, 0, 0);
                oacc[dn] = __builtin_amdgcn_mfma_f32_16x16x32_bf16(pah, vl, oacc[dn], 0, 0, 0);
                oacc[dn] = __builtin_amdgcn_mfma_f32_16x16x32_bf16(pal, vh, oacc[dn], 0, 0, 0);
            }
        }
    }

    // epilogue: normalize (l for q=row via shuffle), fsplit, write split planes
    float invr[4];
    #pragma unroll
    for (int r = 0; r < 4; ++r) invr[r] = 1.f / __shfl(l_run, l4 * 4 + r);
    #pragma unroll
    for (int r = 0; r < 4; ++r) {
        const int q = q0 + wq0 + l4 * 4 + r;
        const size_t row = ((size_t)(bb * SEQ + q)) * EMB + hh * HDIM;
        #pragma unroll
        for (int dn = 0; dn < 4; ++dn) {
            short hi, lo; fsplit(oacc[dn][r] * invr[r], hi, lo);
            Oh[row + dn * 16 + l15] = hi;
            Ol[row + dn * 16 + l15] = lo;
        }
    }
}

// ---------------------------------------------------------------------------
extern "C" void kernel_launch(void* const* d_in, const int* in_sizes, int n_in,
                              void* d_out, int out_size, void* d_ws, size_t ws_size,
                              hipStream_t stream)
{
    const float* x  = (const float*)d_in[0];
    const float* Wk = (const float*)d_in[1];
    const float* Wq = (const float*)d_in[2];
    const float* Wv = (const float*)d_in[3];
    const float* Wu = (const float*)d_in[4];
    const float* bu = (const float*)d_in[5];
    const float* kg = (const float*)d_in[6];
    const float* kb = (const float*)d_in[7];
    const float* qg = (const float*)d_in[8];
    const float* qb = (const float*)d_in[9];
    float* out = (float*)d_out;

    // ws map (64 MB):
    //  [ 0,16M) Xh|Xl   -> reused as Oh|Ol after KQV GEMMs
    //  [16,32M) Kh|Kl
    //  [32,48M) Qh|Ql
    //  [48,64M) W4h (4x2MB) | W4l (4x2MB)
    // d_out doubles as: V^T split panels (KQV z=2 out) -> final fp32 out
    char* w = (char*)d_ws;
    short* XhP = (short*)(w);
    short* XlP = (short*)(w + (8u  << 20));
    short* KhP = (short*)(w + (16u << 20));
    short* KlP = (short*)(w + (24u << 20));
    short* QhP = (short*)(w + (32u << 20));
    short* QlP = (short*)(w + (40u << 20));
    short* W4h = (short*)(w + (48u << 20));
    short* W4l = (short*)(w + (56u << 20));
    short* VTh = (short*)d_out;
    short* VTl = (short*)d_out + (4u << 20);   // +8 MB

    const float inv4 = 0.17677669529663687f;   // 1024^(-1/4)

    cvt_split<<<4096, 256, 0, stream>>>(x, XhP, XlP);
    cvt_w4<<<dim3(1024, 4), 256, 0, stream>>>(Wk, Wq, Wv, Wu, W4h, W4l);

    gemm_kqv<<<dim3(GN / 128, MROWS / 128, 3), 256, 0, stream>>>(
        XhP, XlP, W4h, W4l, kg, kb, qg, qb, inv4,
        KhP, KlP, QhP, QlP, VTh, VTl);

    attn_mfma<<<dim3(SEQ / 128, BATCH * NHEADS), 512, 0, stream>>>(
        QhP, QlP, KhP, KlP, VTh, VTl, XhP, XlP);

    gemm_out<<<dim3(GN / 128, MROWS / 64), 256, 0, stream>>>(
        XhP, XlP, W4h + (3u << 20), W4l + (3u << 20), bu, out);
}

// Round 12
// 247.530 us; speedup vs baseline: 1.8409x; 1.0369x over previous
//
#include <hip/hip_runtime.h>
#include <math.h>

#define EMB 1024
#define NHEADS 16
#define HDIM 64
#define BATCH 2
#define SEQ 2048
#define MROWS (BATCH*SEQ)   /* 4096 */
#define LN_EPS 1e-5f
#define GK 1024
#define GN 1024

typedef __attribute__((ext_vector_type(8))) short bf16x8;
typedef __attribute__((ext_vector_type(4))) short s16x4;
typedef __attribute__((ext_vector_type(4))) float f32x4;
typedef __attribute__((ext_vector_type(16))) float f32x16;
typedef __attribute__((ext_vector_type(4))) int int4v;

__device__ __forceinline__ short f2bf(float f) {     // RNE float->bf16
    union { float f; unsigned u; } v; v.f = f;
    unsigned r = v.u + 0x7FFFu + ((v.u >> 16) & 1u);
    return (short)(r >> 16);
}
__device__ __forceinline__ float bf2f(short s) {
    union { unsigned u; float f; } v; v.u = ((unsigned)(unsigned short)s) << 16;
    return v.f;
}
// truncating split: f = hi + lo + err, |err| <~ 2^-17 |f|
__device__ __forceinline__ void fsplit(float f, short& hi, short& lo) {
    const unsigned u = __float_as_uint(f);
    hi = (short)(u >> 16);
    const float r = f - __uint_as_float(u & 0xFFFF0000u);   // exact
    lo = (short)(__float_as_uint(r) >> 16);
}
__device__ __forceinline__ unsigned pk2(short a, short b) {
    return (unsigned)(unsigned short)a | ((unsigned)(unsigned short)b << 16);
}

__device__ __forceinline__ void gload16(const short* g, short* l) {
    __builtin_amdgcn_global_load_lds(
        (const __attribute__((address_space(1))) unsigned*)g,
        (__attribute__((address_space(3))) unsigned*)l, 16, 0, 0);
}

#define MFMA32(a, b, c) __builtin_amdgcn_mfma_f32_32x32x16_bf16(a, b, c, 0, 0, 0)

// ---------------------------------------------------------------------------
// fp32 -> split-bf16 planes. x input.
// ---------------------------------------------------------------------------
__global__ __launch_bounds__(256)
void cvt_split(const float* __restrict__ X, short* __restrict__ H,
               short* __restrict__ L)
{
    const size_t i = (size_t)blockIdx.x * 256 + threadIdx.x;
    const float4 v = *(const float4*)&X[i * 4];
    s16x4 h, l;
    short th, tl;
    fsplit(v.x, th, tl); h[0] = th; l[0] = tl;
    fsplit(v.y, th, tl); h[1] = th; l[1] = tl;
    fsplit(v.z, th, tl); h[2] = th; l[2] = tl;
    fsplit(v.w, th, tl); h[3] = th; l[3] = tl;
    *(s16x4*)&H[i * 4] = h;
    *(s16x4*)&L[i * 4] = l;
}

// all four weights -> 4 slots of (1M shorts) in H/L planes. grid (1024, 4)
__global__ __launch_bounds__(256)
void cvt_w4(const float* __restrict__ W0, const float* __restrict__ W1,
            const float* __restrict__ W2, const float* __restrict__ W3,
            short* __restrict__ H, short* __restrict__ L)
{
    const int z = blockIdx.y;
    const float* W = (z == 0) ? W0 : (z == 1) ? W1 : (z == 2) ? W2 : W3;
    const size_t i = (size_t)blockIdx.x * 256 + threadIdx.x;
    const size_t o = ((size_t)z << 20) + i * 4;
    const float4 v = *(const float4*)&W[i * 4];
    s16x4 h, l;
    short th, tl;
    fsplit(v.x, th, tl); h[0] = th; l[0] = tl;
    fsplit(v.y, th, tl); h[1] = th; l[1] = tl;
    fsplit(v.z, th, tl); h[2] = th; l[2] = tl;
    fsplit(v.w, th, tl); h[3] = th; l[3] = tl;
    *(s16x4*)&H[o] = h;
    *(s16x4*)&L[o] = l;
}

// ---------------------------------------------------------------------------
// Fused K/Q/V split-bf16 MFMA GEMM (unchanged, measured).
// ---------------------------------------------------------------------------
__global__ __launch_bounds__(256, 3)
void gemm_kqv(const short* __restrict__ Xh, const short* __restrict__ Xl,
              const short* __restrict__ W4h, const short* __restrict__ W4l,
              const float* __restrict__ kg, const float* __restrict__ kb,
              const float* __restrict__ qg, const float* __restrict__ qb,
              float scale,
              short* __restrict__ KhP, short* __restrict__ KlP,
              short* __restrict__ QhP, short* __restrict__ QlP,
              short* __restrict__ VTh, short* __restrict__ VTl)
{
    __shared__ short AhS[128][32], AlS[128][32], BhS[128][32], BlS[128][32];

    const int t   = threadIdx.x;
    const int ln  = t & 63, wv = t >> 6;
    const int l15 = ln & 15, l4 = ln >> 4;
    const int m0  = blockIdx.y * 128;
    const int n0  = blockIdx.x * 128;
    const int z   = blockIdx.z;
    const int wr  = (wv >> 1) * 64, wc = (wv & 1) * 64;

    const short* Bh = W4h + ((size_t)z << 20);
    const short* Bl = W4l + ((size_t)z << 20);

    const short* gplane = (wv == 0) ? Xh : (wv == 1) ? Xl : (wv == 2) ? Bh : Bl;
    const int    grow0  = (wv < 2) ? m0 : n0;
    short* lplane = (wv == 0) ? &AhS[0][0] : (wv == 1) ? &AlS[0][0]
                  : (wv == 2) ? &BhS[0][0] : &BlS[0][0];

    f32x4 acc[4][4];
    #pragma unroll
    for (int i = 0; i < 4; ++i)
        #pragma unroll
        for (int j = 0; j < 4; ++j) acc[i][j] = (f32x4){0.f, 0.f, 0.f, 0.f};

    for (int k0 = 0; k0 < GK; k0 += 32) {
        __syncthreads();
        #pragma unroll
        for (int s = 0; s < 8; ++s) {
            const int chunk = s * 64 + ln;
            const int r = chunk >> 2, c = chunk & 3;
            gload16(gplane + (size_t)(grow0 + r) * GK + k0 + c * 8,
                    lplane + s * 512);
        }
        __syncthreads();

        bf16x8 ah[4], al[4], bh[4], bl[4];
        #pragma unroll
        for (int f = 0; f < 4; ++f) {
            ah[f] = *(const bf16x8*)&AhS[wr + f * 16 + l15][l4 * 8];
            al[f] = *(const bf16x8*)&AlS[wr + f * 16 + l15][l4 * 8];
            bh[f] = *(const bf16x8*)&BhS[wc + f * 16 + l15][l4 * 8];
            bl[f] = *(const bf16x8*)&BlS[wc + f * 16 + l15][l4 * 8];
        }
        #pragma unroll
        for (int i = 0; i < 4; ++i)
            #pragma unroll
            for (int j = 0; j < 4; ++j) {
                acc[i][j] = __builtin_amdgcn_mfma_f32_16x16x32_bf16(ah[i], bh[j], acc[i][j], 0, 0, 0);
                acc[i][j] = __builtin_amdgcn_mfma_f32_16x16x32_bf16(ah[i], bl[j], acc[i][j], 0, 0, 0);
                acc[i][j] = __builtin_amdgcn_mfma_f32_16x16x32_bf16(al[i], bh[j], acc[i][j], 0, 0, 0);
            }
    }

    if (z < 2) {
        const float* gamma = (z == 0) ? kg : qg;
        const float* beta  = (z == 0) ? kb : qb;
        short* OutH = (z == 0) ? KhP : QhP;
        short* OutL = (z == 0) ? KlP : QlP;
        const int n_head = (n0 + wc) >> 6;
        float g4[4], b4[4];
        #pragma unroll
        for (int f = 0; f < 4; ++f) {
            g4[f] = gamma[f * 16 + l15];
            b4[f] = beta [f * 16 + l15];
        }
        #pragma unroll
        for (int i = 0; i < 4; ++i)
            #pragma unroll
            for (int j = 0; j < 4; ++j) {
                const float v0 = acc[i][0][j], v1 = acc[i][1][j];
                const float v2 = acc[i][2][j], v3 = acc[i][3][j];
                float s1 = v0 + v1 + v2 + v3;
                float s2 = v0*v0 + v1*v1 + v2*v2 + v3*v3;
                s1 += __shfl_xor(s1, 1); s2 += __shfl_xor(s2, 1);
                s1 += __shfl_xor(s1, 2); s2 += __shfl_xor(s2, 2);
                s1 += __shfl_xor(s1, 4); s2 += __shfl_xor(s2, 4);
                s1 += __shfl_xor(s1, 8); s2 += __shfl_xor(s2, 8);
                const float mu  = s1 * (1.f / 64.f);
                const float var = s2 * (1.f / 64.f) - mu * mu;
                const float rs  = rsqrtf(var + LN_EPS);
                const int m = m0 + wr + i * 16 + l4 * 4 + j;   // m = b*SEQ + t
                const size_t orow =
                    ((size_t)((m >> 11) * NHEADS + n_head) * SEQ + (m & (SEQ - 1))) * HDIM;
                #pragma unroll
                for (int f = 0; f < 4; ++f) {
                    const float y = ((acc[i][f][j] - mu) * rs * g4[f] + b4[f]) * scale;
                    short hi, lo; fsplit(y, hi, lo);
                    OutH[orow + f * 16 + l15] = hi;
                    OutL[orow + f * 16 + l15] = lo;
                }
            }
    } else {
        #pragma unroll
        for (int i = 0; i < 4; ++i)
            #pragma unroll
            for (int f = 0; f < 4; ++f) {
                s16x4 h4, l4v;
                #pragma unroll
                for (int j = 0; j < 4; ++j) {
                    short hi, lo; fsplit(acc[i][f][j], hi, lo);
                    h4[j] = hi; l4v[j] = lo;
                }
                const int n  = n0 + wc + f * 16 + l15;
                const int hh = n >> 6, dd = n & 63;
                const int mb = m0 + wr + i * 16 + l4 * 4;      // j=0 row
                const size_t oa =
                    (((size_t)((mb >> 11) * NHEADS + hh)) * HDIM + dd) * SEQ + (mb & (SEQ - 1));
                *(s16x4*)&VTh[oa] = h4;
                *(s16x4*)&VTl[oa] = l4v;
            }
    }
}

// ---------------------------------------------------------------------------
// Final GEMM (unchanged).
// ---------------------------------------------------------------------------
__global__ __launch_bounds__(256, 2)
void gemm_out(const short* __restrict__ Ah, const short* __restrict__ Al,
              const short* __restrict__ Bh, const short* __restrict__ Bl,
              const float* __restrict__ bias, float* __restrict__ OutF)
{
    __shared__ short AhS[64][32], AlS[64][32], BhS[128][32], BlS[128][32];

    const int t   = threadIdx.x;
    const int ln  = t & 63, wv = t >> 6;
    const int l15 = ln & 15, l4 = ln >> 4;
    const int m0  = blockIdx.y * 64;
    const int n0  = blockIdx.x * 128;
    const int wr  = (wv >> 1) * 32, wc = (wv & 1) * 64;

    const short* gplane = (wv == 0) ? Ah : (wv == 1) ? Al : (wv == 2) ? Bh : Bl;
    const int    grow0  = (wv < 2) ? m0 : n0;
    const int    nseg   = (wv < 2) ? 4 : 8;
    short* lplane = (wv == 0) ? &AhS[0][0] : (wv == 1) ? &AlS[0][0]
                  : (wv == 2) ? &BhS[0][0] : &BlS[0][0];

    f32x4 acc[2][4];
    #pragma unroll
    for (int i = 0; i < 2; ++i)
        #pragma unroll
        for (int j = 0; j < 4; ++j) acc[i][j] = (f32x4){0.f, 0.f, 0.f, 0.f};

    for (int k0 = 0; k0 < GK; k0 += 32) {
        __syncthreads();
        for (int s = 0; s < nseg; ++s) {
            const int chunk = s * 64 + ln;
            const int r = chunk >> 2, c = chunk & 3;
            gload16(gplane + (size_t)(grow0 + r) * GK + k0 + c * 8,
                    lplane + s * 512);
        }
        __syncthreads();

        bf16x8 ah[2], al[2], bh[4], bl[4];
        #pragma unroll
        for (int f = 0; f < 2; ++f) {
            ah[f] = *(const bf16x8*)&AhS[wr + f * 16 + l15][l4 * 8];
            al[f] = *(const bf16x8*)&AlS[wr + f * 16 + l15][l4 * 8];
        }
        #pragma unroll
        for (int f = 0; f < 4; ++f) {
            bh[f] = *(const bf16x8*)&BhS[wc + f * 16 + l15][l4 * 8];
            bl[f] = *(const bf16x8*)&BlS[wc + f * 16 + l15][l4 * 8];
        }
        #pragma unroll
        for (int i = 0; i < 2; ++i)
            #pragma unroll
            for (int j = 0; j < 4; ++j) {
                acc[i][j] = __builtin_amdgcn_mfma_f32_16x16x32_bf16(ah[i], bh[j], acc[i][j], 0, 0, 0);
                acc[i][j] = __builtin_amdgcn_mfma_f32_16x16x32_bf16(ah[i], bl[j], acc[i][j], 0, 0, 0);
                acc[i][j] = __builtin_amdgcn_mfma_f32_16x16x32_bf16(al[i], bh[j], acc[i][j], 0, 0, 0);
            }
    }

    float b4[4];
    #pragma unroll
    for (int f = 0; f < 4; ++f) b4[f] = bias[n0 + wc + f * 16 + l15];
    #pragma unroll
    for (int i = 0; i < 2; ++i)
        #pragma unroll
        for (int j = 0; j < 4; ++j) {
            const int m = m0 + wr + i * 16 + l4 * 4 + j;
            const size_t row = (size_t)m * GN + n0 + wc;
            #pragma unroll
            for (int f = 0; f < 4; ++f)
                OutF[row + f * 16 + l15] = acc[i][f][j] + b4[f];
        }
}

// ---------------------------------------------------------------------------
// Causal flash attention, split-bf16 on mfma_f32_32x32x16_bf16 (swapped:
// mfma(K,Q) / mfma(V',P)). 4 waves x 32-q stripe, QBLK=128, KVBLK=64.
// C layout (m74/m101): col=lane&31 (=q), row=(reg&3)+8*(reg>>2)+4*(lane>>5).
// A operand: row=lane&31, k=(lane>>5)*8+j (K=16). B: col=lane&31, same k.
//  - Softmax is per-lane (q = lane&31); only shfl_xor(.,32) cross-half.
//  - P goes C-regs -> B-frags IN REGISTER: per 16-k step ks, lane packs its
//    reg-groups 2(ks&1) ("A" pair) and 2(ks&1)+1 ("B" pair) as bf16 pairs;
//    one shfl_xor(.,32) of (lower? B : A) builds the frag:
//    lower = (A0,A1,recv), upper = (recv,B0,B1). No P LDS at all.
//  - K/V tiles [64][64] shorts, 16B-granule XOR swizzle (g ^= row&7) on both
//    staged write and frag read. LDS 32KB/block -> 2 blocks/CU (grid 512).
//  - T14 reg-prefetch of next K/V tile (8x int4v).
// ---------------------------------------------------------------------------
__global__ __launch_bounds__(256, 2)
void attn_mfma(const short* __restrict__ Qh, const short* __restrict__ Ql,
               const short* __restrict__ Kh, const short* __restrict__ Kl,
               const short* __restrict__ Vh, const short* __restrict__ Vl,
               short* __restrict__ Oh, short* __restrict__ Ol)
{
    __shared__ short KhS[64][64], KlS[64][64];
    __shared__ short VhS[64][64], VlS[64][64];

    const int t    = threadIdx.x;
    const int lane = t & 63, wv = t >> 6;            // 4 waves
    const int l31  = lane & 31, hb = lane >> 5;
    const int qt   = (int)gridDim.x - 1 - (int)blockIdx.x;   // heavy first
    const int bh   = blockIdx.y;
    const int bb   = bh >> 4, hh = bh & 15;
    const int q0   = qt * 128;
    const int wq0  = wv * 32;

    const size_t kpan = (size_t)bh * SEQ * HDIM;   // [t][d] panels (Q,K)
    const size_t vpan = (size_t)bh * HDIM * SEQ;   // [d][t] panels (V^T)

    // staging: 2 granule-passes per thread per plane (64x64 shorts = 512 x16B)
    const int sr0  = t >> 3, sr1 = 32 + (t >> 3);
    const int scg  = t & 7;
    const int soff = scg * 8;
    const int lc0  = (scg ^ (sr0 & 7)) * 8;
    const int lc1  = (scg ^ (sr1 & 7)) * 8;

    // Q B-frags: col q = q0+wq0+l31, k-dim d = ds*16 + hb*8 + j
    bf16x8 qfh[4], qfl[4];
    {
        const size_t qrow = kpan + (size_t)(q0 + wq0 + l31) * HDIM;
        #pragma unroll
        for (int ds = 0; ds < 4; ++ds) {
            qfh[ds] = *(const bf16x8*)&Qh[qrow + ds * 16 + hb * 8];
            qfl[ds] = *(const bf16x8*)&Ql[qrow + ds * 16 + hb * 8];
        }
    }

    f32x16 oacc0 = (f32x16)(0.0f), oacc1 = (f32x16)(0.0f);
    float m_run = -1e30f, l_run = 0.f;

    const int NT = 2 * qt + 2;

    int4v pKh0, pKh1, pKl0, pKl1, pVh0, pVh1, pVl0, pVl1;
    {
        pKh0 = *(const int4v*)&Kh[kpan + (size_t)sr0 * HDIM + soff];
        pKh1 = *(const int4v*)&Kh[kpan + (size_t)sr1 * HDIM + soff];
        pKl0 = *(const int4v*)&Kl[kpan + (size_t)sr0 * HDIM + soff];
        pKl1 = *(const int4v*)&Kl[kpan + (size_t)sr1 * HDIM + soff];
        pVh0 = *(const int4v*)&Vh[vpan + (size_t)sr0 * SEQ + soff];
        pVh1 = *(const int4v*)&Vh[vpan + (size_t)sr1 * SEQ + soff];
        pVl0 = *(const int4v*)&Vl[vpan + (size_t)sr0 * SEQ + soff];
        pVl1 = *(const int4v*)&Vl[vpan + (size_t)sr1 * SEQ + soff];
    }

    for (int kt = 0; kt < NT; ++kt) {
        const int k0 = kt * 64;

        __syncthreads();           // all waves done reading prev K/V

        *(int4v*)&KhS[sr0][lc0] = pKh0;  *(int4v*)&KhS[sr1][lc1] = pKh1;
        *(int4v*)&KlS[sr0][lc0] = pKl0;  *(int4v*)&KlS[sr1][lc1] = pKl1;
        *(int4v*)&VhS[sr0][lc0] = pVh0;  *(int4v*)&VhS[sr1][lc1] = pVh1;
        *(int4v*)&VlS[sr0][lc0] = pVl0;  *(int4v*)&VlS[sr1][lc1] = pVl1;

        if (kt + 1 < NT) {         // T14: issue next tile's loads under compute
            const int kn = k0 + 64;
            pKh0 = *(const int4v*)&Kh[kpan + (size_t)(kn + sr0) * HDIM + soff];
            pKh1 = *(const int4v*)&Kh[kpan + (size_t)(kn + sr1) * HDIM + soff];
            pKl0 = *(const int4v*)&Kl[kpan + (size_t)(kn + sr0) * HDIM + soff];
            pKl1 = *(const int4v*)&Kl[kpan + (size_t)(kn + sr1) * HDIM + soff];
            pVh0 = *(const int4v*)&Vh[vpan + (size_t)sr0 * SEQ + kn + soff];
            pVh1 = *(const int4v*)&Vh[vpan + (size_t)sr1 * SEQ + kn + soff];
            pVl0 = *(const int4v*)&Vl[vpan + (size_t)sr0 * SEQ + kn + soff];
            pVl1 = *(const int4v*)&Vl[vpan + (size_t)sr1 * SEQ + kn + soff];
        }
        __syncthreads();           // current tile's LDS ready

        if (k0 > q0 + wq0 + 31) continue;   // tile entirely future for wave

        // ---- QK^T: s0 (k rows 0-31), s1 (k rows 32-63); cols = q ----
        f32x16 s0 = (f32x16)(0.0f), s1 = (f32x16)(0.0f);
        #pragma unroll
        for (int ds = 0; ds < 4; ++ds) {
            const int g = ((ds * 2 + hb) ^ (l31 & 7)) * 8;
            const bf16x8 kh0 = *(const bf16x8*)&KhS[l31][g];
            const bf16x8 kl0 = *(const bf16x8*)&KlS[l31][g];
            const bf16x8 kh1 = *(const bf16x8*)&KhS[32 + l31][g];
            const bf16x8 kl1 = *(const bf16x8*)&KlS[32 + l31][g];
            s0 = MFMA32(kh0, qfh[ds], s0);
            s0 = MFMA32(kh0, qfl[ds], s0);
            s0 = MFMA32(kl0, qfh[ds], s0);
            s1 = MFMA32(kh1, qfh[ds], s1);
            s1 = MFMA32(kh1, qfl[ds], s1);
            s1 = MFMA32(kl1, qfh[ds], s1);
        }

        // ---- causal mask (diag kept) ----
        if (k0 + 63 > q0 + wq0) {
            const int qg = q0 + wq0 + l31;
            #pragma unroll
            for (int reg = 0; reg < 16; ++reg) {
                const int kk = k0 + (reg & 3) + 8 * (reg >> 2) + 4 * hb;
                if (kk > qg)      s0[reg] = -1e30f;
                if (kk + 32 > qg) s1[reg] = -1e30f;
            }
        }

        // ---- online softmax (lane-local q; halves share q via shfl 32) ----
        {
            float mx = -1e30f;
            #pragma unroll
            for (int reg = 0; reg < 16; ++reg)
                mx = fmaxf(mx, fmaxf(s0[reg], s1[reg]));
            mx = fmaxf(mx, __shfl_xor(mx, 32));
            const float mnew = fmaxf(m_run, mx);
            const float scf  = __expf(m_run - mnew);
            m_run = mnew;
            float ls = 0.f;
            #pragma unroll
            for (int reg = 0; reg < 16; ++reg) {
                const float p0 = __expf(s0[reg] - mnew);
                const float p1 = __expf(s1[reg] - mnew);
                s0[reg] = p0; s1[reg] = p1;
                ls += p0 + p1;
            }
            ls += __shfl_xor(ls, 32);
            l_run = l_run * scf + ls;
            #pragma unroll
            for (int reg = 0; reg < 16; ++reg) {
                oacc0[reg] *= scf;
                oacc1[reg] *= scf;
            }
        }

        // ---- PV: per 16-k step, build P B-frag in-register, 6 MFMAs ----
        #pragma unroll
        for (int ks = 0; ks < 4; ++ks) {
            short h8[8], l8[8];
            #pragma unroll
            for (int a = 0; a < 8; ++a) {
                const float p = (ks >= 2) ? s1[(ks & 1) * 8 + a]
                                          : s0[(ks & 1) * 8 + a];
                short hi, lo; fsplit(p, hi, lo);
                h8[a] = hi; l8[a] = lo;
            }
            const unsigned hA0 = pk2(h8[0], h8[1]), hA1 = pk2(h8[2], h8[3]);
            const unsigned hB0 = pk2(h8[4], h8[5]), hB1 = pk2(h8[6], h8[7]);
            const unsigned lA0 = pk2(l8[0], l8[1]), lA1 = pk2(l8[2], l8[3]);
            const unsigned lB0 = pk2(l8[4], l8[5]), lB1 = pk2(l8[6], l8[7]);
            const unsigned hr0 = (unsigned)__shfl_xor((int)(hb ? hA0 : hB0), 32);
            const unsigned hr1 = (unsigned)__shfl_xor((int)(hb ? hA1 : hB1), 32);
            const unsigned lr0 = (unsigned)__shfl_xor((int)(hb ? lA0 : lB0), 32);
            const unsigned lr1 = (unsigned)__shfl_xor((int)(hb ? lA1 : lB1), 32);
            const int4v wih = (int4v){(int)(hb ? hr0 : hA0), (int)(hb ? hr1 : hA1),
                                      (int)(hb ? hB0 : hr0), (int)(hb ? hB1 : hr1)};
            const int4v wil = (int4v){(int)(hb ? lr0 : lA0), (int)(hb ? lr1 : lA1),
                                      (int)(hb ? lB0 : lr0), (int)(hb ? lB1 : lr1)};
            const bf16x8 pfh = __builtin_bit_cast(bf16x8, wih);
            const bf16x8 pfl = __builtin_bit_cast(bf16x8, wil);

            const int gv = ((ks * 2 + hb) ^ (l31 & 7)) * 8;
            const bf16x8 vh0 = *(const bf16x8*)&VhS[l31][gv];
            const bf16x8 vl0 = *(const bf16x8*)&VlS[l31][gv];
            const bf16x8 vh1 = *(const bf16x8*)&VhS[32 + l31][gv];
            const bf16x8 vl1 = *(const bf16x8*)&VlS[32 + l31][gv];
            oacc0 = MFMA32(vh0, pfh, oacc0);
            oacc0 = MFMA32(vh0, pfl, oacc0);
            oacc0 = MFMA32(vl0, pfh, oacc0);
            oacc1 = MFMA32(vh1, pfh, oacc1);
            oacc1 = MFMA32(vh1, pfl, oacc1);
            oacc1 = MFMA32(vl1, pfh, oacc1);
        }
    }

    // epilogue: q = lane's column; d = (reg&3)+8*(reg>>2)+4*hb (+32 for oacc1)
    const float inv = 1.f / l_run;
    const int q = q0 + wq0 + l31;
    const size_t row = ((size_t)(bb * SEQ + q)) * EMB + hh * HDIM;
    #pragma unroll
    for (int db = 0; db < 2; ++db)
        #pragma unroll
        for (int b = 0; b < 4; ++b) {
            s16x4 h4, l4v;
            #pragma unroll
            for (int a = 0; a < 4; ++a) {
                const float v = (db ? oacc1[4 * b + a] : oacc0[4 * b + a]) * inv;
                short hi, lo; fsplit(v, hi, lo);
                h4[a] = hi; l4v[a] = lo;
            }
            const int d0 = db * 32 + 8 * b + 4 * hb;
            *(s16x4*)&Oh[row + d0] = h4;
            *(s16x4*)&Ol[row + d0] = l4v;
        }
}

// ---------------------------------------------------------------------------
extern "C" void kernel_launch(void* const* d_in, const int* in_sizes, int n_in,
                              void* d_out, int out_size, void* d_ws, size_t ws_size,
                              hipStream_t stream)
{
    const float* x  = (const float*)d_in[0];
    const float* Wk = (const float*)d_in[1];
    const float* Wq = (const float*)d_in[2];
    const float* Wv = (const float*)d_in[3];
    const float* Wu = (const float*)d_in[4];
    const float* bu = (const float*)d_in[5];
    const float* kg = (const float*)d_in[6];
    const float* kb = (const float*)d_in[7];
    const float* qg = (const float*)d_in[8];
    const float* qb = (const float*)d_in[9];
    float* out = (float*)d_out;

    // ws map (64 MB):
    //  [ 0,16M) Xh|Xl   -> reused as Oh|Ol after KQV GEMMs
    //  [16,32M) Kh|Kl
    //  [32,48M) Qh|Ql
    //  [48,64M) W4h (4x2MB) | W4l (4x2MB)
    // d_out doubles as: V^T split panels (KQV z=2 out) -> final fp32 out
    char* w = (char*)d_ws;
    short* XhP = (short*)(w);
    short* XlP = (short*)(w + (8u  << 20));
    short* KhP = (short*)(w + (16u << 20));
    short* KlP = (short*)(w + (24u << 20));
    short* QhP = (short*)(w + (32u << 20));
    short* QlP = (short*)(w + (40u << 20));
    short* W4h = (short*)(w + (48u << 20));
    short* W4l = (short*)(w + (56u << 20));
    short* VTh = (short*)d_out;
    short* VTl = (short*)d_out + (4u << 20);   // +8 MB

    const float inv4 = 0.17677669529663687f;   // 1024^(-1/4)

    cvt_split<<<4096, 256, 0, stream>>>(x, XhP, XlP);
    cvt_w4<<<dim3(1024, 4), 256, 0, stream>>>(Wk, Wq, Wv, Wu, W4h, W4l);

    gemm_kqv<<<dim3(GN / 128, MROWS / 128, 3), 256, 0, stream>>>(
        XhP, XlP, W4h, W4l, kg, kb, qg, qb, inv4,
        KhP, KlP, QhP, QlP, VTh, VTl);

    attn_mfma<<<dim3(SEQ / 128, BATCH * NHEADS), 256, 0, stream>>>(
        QhP, QlP, KhP, KlP, VTh, VTl, XhP, XlP);

    gemm_out<<<dim3(GN / 128, MROWS / 64), 256, 0, stream>>>(
        XhP, XlP, W4h + (3u << 20), W4l + (3u << 20), bu, out);
}

// Round 15
// 219.970 us; speedup vs baseline: 2.0716x; 1.1253x over previous
//
#include <hip/hip_runtime.h>
#include <math.h>

#define EMB 1024
#define NHEADS 16
#define HDIM 64
#define BATCH 2
#define SEQ 2048
#define MROWS (BATCH*SEQ)   /* 4096 */
#define LN_EPS 1e-5f
#define GK 1024
#define GN 1024

typedef __attribute__((ext_vector_type(8))) short bf16x8;
typedef __attribute__((ext_vector_type(4))) short s16x4;
typedef __attribute__((ext_vector_type(4))) float f32x4;
typedef __attribute__((ext_vector_type(16))) float f32x16;
typedef __attribute__((ext_vector_type(4))) int int4v;

__device__ __forceinline__ short f2bf(float f) {     // RNE float->bf16
    union { float f; unsigned u; } v; v.f = f;
    unsigned r = v.u + 0x7FFFu + ((v.u >> 16) & 1u);
    return (short)(r >> 16);
}
__device__ __forceinline__ float bf2f(short s) {
    union { unsigned u; float f; } v; v.u = ((unsigned)(unsigned short)s) << 16;
    return v.f;
}
// truncating split: f = hi + lo + err, |err| <~ 2^-17 |f|
__device__ __forceinline__ void fsplit(float f, short& hi, short& lo) {
    const unsigned u = __float_as_uint(f);
    hi = (short)(u >> 16);
    const float r = f - __uint_as_float(u & 0xFFFF0000u);   // exact
    lo = (short)(__float_as_uint(r) >> 16);
}
__device__ __forceinline__ unsigned pk2(short a, short b) {
    return (unsigned)(unsigned short)a | ((unsigned)(unsigned short)b << 16);
}

__device__ __forceinline__ void gload16(const short* g, short* l) {
    __builtin_amdgcn_global_load_lds(
        (const __attribute__((address_space(1))) unsigned*)g,
        (__attribute__((address_space(3))) unsigned*)l, 16, 0, 0);
}

#define MFMA32(a, b, c) __builtin_amdgcn_mfma_f32_32x32x16_bf16(a, b, c, 0, 0, 0)

// ---------------------------------------------------------------------------
// fp32 -> split-bf16 planes. x input.
// ---------------------------------------------------------------------------
__global__ __launch_bounds__(256)
void cvt_split(const float* __restrict__ X, short* __restrict__ H,
               short* __restrict__ L)
{
    const size_t i = (size_t)blockIdx.x * 256 + threadIdx.x;
    const float4 v = *(const float4*)&X[i * 4];
    s16x4 h, l;
    short th, tl;
    fsplit(v.x, th, tl); h[0] = th; l[0] = tl;
    fsplit(v.y, th, tl); h[1] = th; l[1] = tl;
    fsplit(v.z, th, tl); h[2] = th; l[2] = tl;
    fsplit(v.w, th, tl); h[3] = th; l[3] = tl;
    *(s16x4*)&H[i * 4] = h;
    *(s16x4*)&L[i * 4] = l;
}

// all four weights -> 4 slots of (1M shorts) in H/L planes. grid (1024, 4)
__global__ __launch_bounds__(256)
void cvt_w4(const float* __restrict__ W0, const float* __restrict__ W1,
            const float* __restrict__ W2, const float* __restrict__ W3,
            short* __restrict__ H, short* __restrict__ L)
{
    const int z = blockIdx.y;
    const float* W = (z == 0) ? W0 : (z == 1) ? W1 : (z == 2) ? W2 : W3;
    const size_t i = (size_t)blockIdx.x * 256 + threadIdx.x;
    const size_t o = ((size_t)z << 20) + i * 4;
    const float4 v = *(const float4*)&W[i * 4];
    s16x4 h, l;
    short th, tl;
    fsplit(v.x, th, tl); h[0] = th; l[0] = tl;
    fsplit(v.y, th, tl); h[1] = th; l[1] = tl;
    fsplit(v.z, th, tl); h[2] = th; l[2] = tl;
    fsplit(v.w, th, tl); h[3] = th; l[3] = tl;
    *(s16x4*)&H[o] = h;
    *(s16x4*)&L[o] = l;
}

// ---------------------------------------------------------------------------
// Fused K/Q/V split-bf16 MFMA GEMM. z=2 (V^T) writes hi plane only —
// attention consumes V at bf16 precision.
// ---------------------------------------------------------------------------
__global__ __launch_bounds__(256, 3)
void gemm_kqv(const short* __restrict__ Xh, const short* __restrict__ Xl,
              const short* __restrict__ W4h, const short* __restrict__ W4l,
              const float* __restrict__ kg, const float* __restrict__ kb,
              const float* __restrict__ qg, const float* __restrict__ qb,
              float scale,
              short* __restrict__ KhP, short* __restrict__ KlP,
              short* __restrict__ QhP, short* __restrict__ QlP,
              short* __restrict__ VTh)
{
    __shared__ short AhS[128][32], AlS[128][32], BhS[128][32], BlS[128][32];

    const int t   = threadIdx.x;
    const int ln  = t & 63, wv = t >> 6;
    const int l15 = ln & 15, l4 = ln >> 4;
    const int m0  = blockIdx.y * 128;
    const int n0  = blockIdx.x * 128;
    const int z   = blockIdx.z;
    const int wr  = (wv >> 1) * 64, wc = (wv & 1) * 64;

    const short* Bh = W4h + ((size_t)z << 20);
    const short* Bl = W4l + ((size_t)z << 20);

    const short* gplane = (wv == 0) ? Xh : (wv == 1) ? Xl : (wv == 2) ? Bh : Bl;
    const int    grow0  = (wv < 2) ? m0 : n0;
    short* lplane = (wv == 0) ? &AhS[0][0] : (wv == 1) ? &AlS[0][0]
                  : (wv == 2) ? &BhS[0][0] : &BlS[0][0];

    f32x4 acc[4][4];
    #pragma unroll
    for (int i = 0; i < 4; ++i)
        #pragma unroll
        for (int j = 0; j < 4; ++j) acc[i][j] = (f32x4){0.f, 0.f, 0.f, 0.f};

    for (int k0 = 0; k0 < GK; k0 += 32) {
        __syncthreads();
        #pragma unroll
        for (int s = 0; s < 8; ++s) {
            const int chunk = s * 64 + ln;
            const int r = chunk >> 2, c = chunk & 3;
            gload16(gplane + (size_t)(grow0 + r) * GK + k0 + c * 8,
                    lplane + s * 512);
        }
        __syncthreads();

        bf16x8 ah[4], al[4], bh[4], bl[4];
        #pragma unroll
        for (int f = 0; f < 4; ++f) {
            ah[f] = *(const bf16x8*)&AhS[wr + f * 16 + l15][l4 * 8];
            al[f] = *(const bf16x8*)&AlS[wr + f * 16 + l15][l4 * 8];
            bh[f] = *(const bf16x8*)&BhS[wc + f * 16 + l15][l4 * 8];
            bl[f] = *(const bf16x8*)&BlS[wc + f * 16 + l15][l4 * 8];
        }
        #pragma unroll
        for (int i = 0; i < 4; ++i)
            #pragma unroll
            for (int j = 0; j < 4; ++j) {
                acc[i][j] = __builtin_amdgcn_mfma_f32_16x16x32_bf16(ah[i], bh[j], acc[i][j], 0, 0, 0);
                acc[i][j] = __builtin_amdgcn_mfma_f32_16x16x32_bf16(ah[i], bl[j], acc[i][j], 0, 0, 0);
                acc[i][j] = __builtin_amdgcn_mfma_f32_16x16x32_bf16(al[i], bh[j], acc[i][j], 0, 0, 0);
            }
    }

    if (z < 2) {
        const float* gamma = (z == 0) ? kg : qg;
        const float* beta  = (z == 0) ? kb : qb;
        short* OutH = (z == 0) ? KhP : QhP;
        short* OutL = (z == 0) ? KlP : QlP;
        const int n_head = (n0 + wc) >> 6;
        float g4[4], b4[4];
        #pragma unroll
        for (int f = 0; f < 4; ++f) {
            g4[f] = gamma[f * 16 + l15];
            b4[f] = beta [f * 16 + l15];
        }
        #pragma unroll
        for (int i = 0; i < 4; ++i)
            #pragma unroll
            for (int j = 0; j < 4; ++j) {
                const float v0 = acc[i][0][j], v1 = acc[i][1][j];
                const float v2 = acc[i][2][j], v3 = acc[i][3][j];
                float s1 = v0 + v1 + v2 + v3;
                float s2 = v0*v0 + v1*v1 + v2*v2 + v3*v3;
                s1 += __shfl_xor(s1, 1); s2 += __shfl_xor(s2, 1);
                s1 += __shfl_xor(s1, 2); s2 += __shfl_xor(s2, 2);
                s1 += __shfl_xor(s1, 4); s2 += __shfl_xor(s2, 4);
                s1 += __shfl_xor(s1, 8); s2 += __shfl_xor(s2, 8);
                const float mu  = s1 * (1.f / 64.f);
                const float var = s2 * (1.f / 64.f) - mu * mu;
                const float rs  = rsqrtf(var + LN_EPS);
                const int m = m0 + wr + i * 16 + l4 * 4 + j;   // m = b*SEQ + t
                const size_t orow =
                    ((size_t)((m >> 11) * NHEADS + n_head) * SEQ + (m & (SEQ - 1))) * HDIM;
                #pragma unroll
                for (int f = 0; f < 4; ++f) {
                    const float y = ((acc[i][f][j] - mu) * rs * g4[f] + b4[f]) * scale;
                    short hi, lo; fsplit(y, hi, lo);
                    OutH[orow + f * 16 + l15] = hi;
                    OutL[orow + f * 16 + l15] = lo;
                }
            }
    } else {
        // V^T epilogue: hi plane only (attn reads V as plain bf16)
        #pragma unroll
        for (int i = 0; i < 4; ++i)
            #pragma unroll
            for (int f = 0; f < 4; ++f) {
                s16x4 h4;
                #pragma unroll
                for (int j = 0; j < 4; ++j) h4[j] = f2bf(acc[i][f][j]);
                const int n  = n0 + wc + f * 16 + l15;
                const int hh = n >> 6, dd = n & 63;
                const int mb = m0 + wr + i * 16 + l4 * 4;      // j=0 row
                const size_t oa =
                    (((size_t)((mb >> 11) * NHEADS + hh)) * HDIM + dd) * SEQ + (mb & (SEQ - 1));
                *(s16x4*)&VTh[oa] = h4;
            }
    }
}

// ---------------------------------------------------------------------------
// Final GEMM (unchanged).
// ---------------------------------------------------------------------------
__global__ __launch_bounds__(256, 2)
void gemm_out(const short* __restrict__ Ah, const short* __restrict__ Al,
              const short* __restrict__ Bh, const short* __restrict__ Bl,
              const float* __restrict__ bias, float* __restrict__ OutF)
{
    __shared__ short AhS[64][32], AlS[64][32], BhS[128][32], BlS[128][32];

    const int t   = threadIdx.x;
    const int ln  = t & 63, wv = t >> 6;
    const int l15 = ln & 15, l4 = ln >> 4;
    const int m0  = blockIdx.y * 64;
    const int n0  = blockIdx.x * 128;
    const int wr  = (wv >> 1) * 32, wc = (wv & 1) * 64;

    const short* gplane = (wv == 0) ? Ah : (wv == 1) ? Al : (wv == 2) ? Bh : Bl;
    const int    grow0  = (wv < 2) ? m0 : n0;
    const int    nseg   = (wv < 2) ? 4 : 8;
    short* lplane = (wv == 0) ? &AhS[0][0] : (wv == 1) ? &AlS[0][0]
                  : (wv == 2) ? &BhS[0][0] : &BlS[0][0];

    f32x4 acc[2][4];
    #pragma unroll
    for (int i = 0; i < 2; ++i)
        #pragma unroll
        for (int j = 0; j < 4; ++j) acc[i][j] = (f32x4){0.f, 0.f, 0.f, 0.f};

    for (int k0 = 0; k0 < GK; k0 += 32) {
        __syncthreads();
        for (int s = 0; s < nseg; ++s) {
            const int chunk = s * 64 + ln;
            const int r = chunk >> 2, c = chunk & 3;
            gload16(gplane + (size_t)(grow0 + r) * GK + k0 + c * 8,
                    lplane + s * 512);
        }
        __syncthreads();

        bf16x8 ah[2], al[2], bh[4], bl[4];
        #pragma unroll
        for (int f = 0; f < 2; ++f) {
            ah[f] = *(const bf16x8*)&AhS[wr + f * 16 + l15][l4 * 8];
            al[f] = *(const bf16x8*)&AlS[wr + f * 16 + l15][l4 * 8];
        }
        #pragma unroll
        for (int f = 0; f < 4; ++f) {
            bh[f] = *(const bf16x8*)&BhS[wc + f * 16 + l15][l4 * 8];
            bl[f] = *(const bf16x8*)&BlS[wc + f * 16 + l15][l4 * 8];
        }
        #pragma unroll
        for (int i = 0; i < 2; ++i)
            #pragma unroll
            for (int j = 0; j < 4; ++j) {
                acc[i][j] = __builtin_amdgcn_mfma_f32_16x16x32_bf16(ah[i], bh[j], acc[i][j], 0, 0, 0);
                acc[i][j] = __builtin_amdgcn_mfma_f32_16x16x32_bf16(ah[i], bl[j], acc[i][j], 0, 0, 0);
                acc[i][j] = __builtin_amdgcn_mfma_f32_16x16x32_bf16(al[i], bh[j], acc[i][j], 0, 0, 0);
            }
    }

    float b4[4];
    #pragma unroll
    for (int f = 0; f < 4; ++f) b4[f] = bias[n0 + wc + f * 16 + l15];
    #pragma unroll
    for (int i = 0; i < 2; ++i)
        #pragma unroll
        for (int j = 0; j < 4; ++j) {
            const int m = m0 + wr + i * 16 + l4 * 4 + j;
            const size_t row = (size_t)m * GN + n0 + wc;
            #pragma unroll
            for (int f = 0; f < 4; ++f)
                OutF[row + f * 16 + l15] = acc[i][f][j] + b4[f];
        }
}

// ---------------------------------------------------------------------------
// Causal flash attention, mfma_f32_32x32x16_bf16 swapped (mfma(K,Q)/(V,P)).
// QK^T keeps 3-term split precision (softmax amplifies S error). PV side is
// hi-only: P quantized to plain bf16 (error ~2^-9, P in [0,1]) and V plain
// bf16 -> PV is 8 MFMAs/tile (was 24), P-pack VALU halved, Vl staging gone.
// LDS 24KB (Kh,Kl,Vh). Everything else as R12 (which passed @0.0156).
// ---------------------------------------------------------------------------
__global__ __launch_bounds__(256, 2)
void attn_mfma(const short* __restrict__ Qh, const short* __restrict__ Ql,
               const short* __restrict__ Kh, const short* __restrict__ Kl,
               const short* __restrict__ Vh,
               short* __restrict__ Oh, short* __restrict__ Ol)
{
    __shared__ short KhS[64][64], KlS[64][64];
    __shared__ short VhS[64][64];

    const int t    = threadIdx.x;
    const int lane = t & 63, wv = t >> 6;            // 4 waves
    const int l31  = lane & 31, hb = lane >> 5;
    const int qt   = (int)gridDim.x - 1 - (int)blockIdx.x;   // heavy first
    const int bh   = blockIdx.y;
    const int bb   = bh >> 4, hh = bh & 15;
    const int q0   = qt * 128;
    const int wq0  = wv * 32;

    const size_t kpan = (size_t)bh * SEQ * HDIM;   // [t][d] panels (Q,K)
    const size_t vpan = (size_t)bh * HDIM * SEQ;   // [d][t] panels (V^T)

    // staging: 2 granule-passes per thread per plane (64x64 shorts = 512 x16B)
    const int sr0  = t >> 3, sr1 = 32 + (t >> 3);
    const int scg  = t & 7;
    const int soff = scg * 8;
    const int lc0  = (scg ^ (sr0 & 7)) * 8;
    const int lc1  = (scg ^ (sr1 & 7)) * 8;

    // Q B-frags: col q = q0+wq0+l31, k-dim d = ds*16 + hb*8 + j
    bf16x8 qfh[4], qfl[4];
    {
        const size_t qrow = kpan + (size_t)(q0 + wq0 + l31) * HDIM;
        #pragma unroll
        for (int ds = 0; ds < 4; ++ds) {
            qfh[ds] = *(const bf16x8*)&Qh[qrow + ds * 16 + hb * 8];
            qfl[ds] = *(const bf16x8*)&Ql[qrow + ds * 16 + hb * 8];
        }
    }

    f32x16 oacc0 = (f32x16)(0.0f), oacc1 = (f32x16)(0.0f);
    float m_run = -1e30f, l_run = 0.f;

    const int NT = 2 * qt + 2;

    int4v pKh0, pKh1, pKl0, pKl1, pVh0, pVh1;
    {
        pKh0 = *(const int4v*)&Kh[kpan + (size_t)sr0 * HDIM + soff];
        pKh1 = *(const int4v*)&Kh[kpan + (size_t)sr1 * HDIM + soff];
        pKl0 = *(const int4v*)&Kl[kpan + (size_t)sr0 * HDIM + soff];
        pKl1 = *(const int4v*)&Kl[kpan + (size_t)sr1 * HDIM + soff];
        pVh0 = *(const int4v*)&Vh[vpan + (size_t)sr0 * SEQ + soff];
        pVh1 = *(const int4v*)&Vh[vpan + (size_t)sr1 * SEQ + soff];
    }

    for (int kt = 0; kt < NT; ++kt) {
        const int k0 = kt * 64;

        __syncthreads();           // all waves done reading prev K/V

        *(int4v*)&KhS[sr0][lc0] = pKh0;  *(int4v*)&KhS[sr1][lc1] = pKh1;
        *(int4v*)&KlS[sr0][lc0] = pKl0;  *(int4v*)&KlS[sr1][lc1] = pKl1;
        *(int4v*)&VhS[sr0][lc0] = pVh0;  *(int4v*)&VhS[sr1][lc1] = pVh1;

        if (kt + 1 < NT) {         // T14: issue next tile's loads under compute
            const int kn = k0 + 64;
            pKh0 = *(const int4v*)&Kh[kpan + (size_t)(kn + sr0) * HDIM + soff];
            pKh1 = *(const int4v*)&Kh[kpan + (size_t)(kn + sr1) * HDIM + soff];
            pKl0 = *(const int4v*)&Kl[kpan + (size_t)(kn + sr0) * HDIM + soff];
            pKl1 = *(const int4v*)&Kl[kpan + (size_t)(kn + sr1) * HDIM + soff];
            pVh0 = *(const int4v*)&Vh[vpan + (size_t)sr0 * SEQ + kn + soff];
            pVh1 = *(const int4v*)&Vh[vpan + (size_t)sr1 * SEQ + kn + soff];
        }
        __syncthreads();           // current tile's LDS ready

        if (k0 > q0 + wq0 + 31) continue;   // tile entirely future for wave

        // ---- QK^T: s0 (k rows 0-31), s1 (k rows 32-63); cols = q ----
        f32x16 s0 = (f32x16)(0.0f), s1 = (f32x16)(0.0f);
        #pragma unroll
        for (int ds = 0; ds < 4; ++ds) {
            const int g = ((ds * 2 + hb) ^ (l31 & 7)) * 8;
            const bf16x8 kh0 = *(const bf16x8*)&KhS[l31][g];
            const bf16x8 kl0 = *(const bf16x8*)&KlS[l31][g];
            const bf16x8 kh1 = *(const bf16x8*)&KhS[32 + l31][g];
            const bf16x8 kl1 = *(const bf16x8*)&KlS[32 + l31][g];
            s0 = MFMA32(kh0, qfh[ds], s0);
            s0 = MFMA32(kh0, qfl[ds], s0);
            s0 = MFMA32(kl0, qfh[ds], s0);
            s1 = MFMA32(kh1, qfh[ds], s1);
            s1 = MFMA32(kh1, qfl[ds], s1);
            s1 = MFMA32(kl1, qfh[ds], s1);
        }

        // ---- causal mask (diag kept) ----
        if (k0 + 63 > q0 + wq0) {
            const int qg = q0 + wq0 + l31;
            #pragma unroll
            for (int reg = 0; reg < 16; ++reg) {
                const int kk = k0 + (reg & 3) + 8 * (reg >> 2) + 4 * hb;
                if (kk > qg)      s0[reg] = -1e30f;
                if (kk + 32 > qg) s1[reg] = -1e30f;
            }
        }

        // ---- online softmax (lane-local q; halves share q via shfl 32) ----
        {
            float mx = -1e30f;
            #pragma unroll
            for (int reg = 0; reg < 16; ++reg)
                mx = fmaxf(mx, fmaxf(s0[reg], s1[reg]));
            mx = fmaxf(mx, __shfl_xor(mx, 32));
            const float mnew = fmaxf(m_run, mx);
            const float scf  = __expf(m_run - mnew);
            m_run = mnew;
            float ls = 0.f;
            #pragma unroll
            for (int reg = 0; reg < 16; ++reg) {
                const float p0 = __expf(s0[reg] - mnew);
                const float p1 = __expf(s1[reg] - mnew);
                s0[reg] = p0; s1[reg] = p1;
                ls += p0 + p1;
            }
            ls += __shfl_xor(ls, 32);
            l_run = l_run * scf + ls;
            #pragma unroll
            for (int reg = 0; reg < 16; ++reg) {
                oacc0[reg] *= scf;
                oacc1[reg] *= scf;
            }
        }

        // ---- PV: per 16-k step, hi-only P B-frag in-register, 2 MFMAs ----
        #pragma unroll
        for (int ks = 0; ks < 4; ++ks) {
            short h8[8];
            #pragma unroll
            for (int a = 0; a < 8; ++a) {
                const float p = (ks >= 2) ? s1[(ks & 1) * 8 + a]
                                          : s0[(ks & 1) * 8 + a];
                h8[a] = f2bf(p);
            }
            const unsigned hA0 = pk2(h8[0], h8[1]), hA1 = pk2(h8[2], h8[3]);
            const unsigned hB0 = pk2(h8[4], h8[5]), hB1 = pk2(h8[6], h8[7]);
            const unsigned hr0 = (unsigned)__shfl_xor((int)(hb ? hA0 : hB0), 32);
            const unsigned hr1 = (unsigned)__shfl_xor((int)(hb ? hA1 : hB1), 32);
            const int4v wih = (int4v){(int)(hb ? hr0 : hA0), (int)(hb ? hr1 : hA1),
                                      (int)(hb ? hB0 : hr0), (int)(hb ? hB1 : hr1)};
            const bf16x8 pfh = __builtin_bit_cast(bf16x8, wih);

            const int gv = ((ks * 2 + hb) ^ (l31 & 7)) * 8;
            const bf16x8 vh0 = *(const bf16x8*)&VhS[l31][gv];
            const bf16x8 vh1 = *(const bf16x8*)&VhS[32 + l31][gv];
            oacc0 = MFMA32(vh0, pfh, oacc0);
            oacc1 = MFMA32(vh1, pfh, oacc1);
        }
    }

    // epilogue: q = lane's column; d = (reg&3)+8*(reg>>2)+4*hb (+32 for oacc1)
    const float inv = 1.f / l_run;
    const int q = q0 + wq0 + l31;
    const size_t row = ((size_t)(bb * SEQ + q)) * EMB + hh * HDIM;
    #pragma unroll
    for (int db = 0; db < 2; ++db)
        #pragma unroll
        for (int b = 0; b < 4; ++b) {
            s16x4 h4, l4v;
            #pragma unroll
            for (int a = 0; a < 4; ++a) {
                const float v = (db ? oacc1[4 * b + a] : oacc0[4 * b + a]) * inv;
                short hi, lo; fsplit(v, hi, lo);
                h4[a] = hi; l4v[a] = lo;
            }
            const int d0 = db * 32 + 8 * b + 4 * hb;
            *(s16x4*)&Oh[row + d0] = h4;
            *(s16x4*)&Ol[row + d0] = l4v;
        }
}

// ---------------------------------------------------------------------------
extern "C" void kernel_launch(void* const* d_in, const int* in_sizes, int n_in,
                              void* d_out, int out_size, void* d_ws, size_t ws_size,
                              hipStream_t stream)
{
    const float* x  = (const float*)d_in[0];
    const float* Wk = (const float*)d_in[1];
    const float* Wq = (const float*)d_in[2];
    const float* Wv = (const float*)d_in[3];
    const float* Wu = (const float*)d_in[4];
    const float* bu = (const float*)d_in[5];
    const float* kg = (const float*)d_in[6];
    const float* kb = (const float*)d_in[7];
    const float* qg = (const float*)d_in[8];
    const float* qb = (const float*)d_in[9];
    float* out = (float*)d_out;

    // ws map (64 MB):
    //  [ 0,16M) Xh|Xl   -> reused as Oh|Ol after KQV GEMMs
    //  [16,32M) Kh|Kl
    //  [32,48M) Qh|Ql
    //  [48,64M) W4h (4x2MB) | W4l (4x2MB)
    // d_out doubles as: V^T hi panel (KQV z=2 out) -> final fp32 out
    char* w = (char*)d_ws;
    short* XhP = (short*)(w);
    short* XlP = (short*)(w + (8u  << 20));
    short* KhP = (short*)(w + (16u << 20));
    short* KlP = (short*)(w + (24u << 20));
    short* QhP = (short*)(w + (32u << 20));
    short* QlP = (short*)(w + (40u << 20));
    short* W4h = (short*)(w + (48u << 20));
    short* W4l = (short*)(w + (56u << 20));
    short* VTh = (short*)d_out;

    const float inv4 = 0.17677669529663687f;   // 1024^(-1/4)

    cvt_split<<<4096, 256, 0, stream>>>(x, XhP, XlP);
    cvt_w4<<<dim3(1024, 4), 256, 0, stream>>>(Wk, Wq, Wv, Wu, W4h, W4l);

    gemm_kqv<<<dim3(GN / 128, MROWS / 128, 3), 256, 0, stream>>>(
        XhP, XlP, W4h, W4l, kg, kb, qg, qb, inv4,
        KhP, KlP, QhP, QlP, VTh);

    attn_mfma<<<dim3(SEQ / 128, BATCH * NHEADS), 256, 0, stream>>>(
        QhP, QlP, KhP, KlP, VTh, XhP, XlP);

    gemm_out<<<dim3(GN / 128, MROWS / 64), 256, 0, stream>>>(
        XhP, XlP, W4h + (3u << 20), W4l + (3u << 20), bu, out);
}